// Round 10
// baseline (137.589 us; speedup 1.0000x reference)
//
#include <hip/hip_runtime.h>
#include <math.h>

#define HDIM 128
#define S 32            // samples per workgroup (4 wave-owned tiles of 8)
#define NT 256
#define ASTR 136        // bf16 row stride (ushort); row pitch 272B = 17*16, b128-aligned
#define PSTR 132        // u32 row stride; row pitch 528B = 33*16

typedef __attribute__((ext_vector_type(8))) short  bf16x8;   // MFMA A/B frag
typedef __attribute__((ext_vector_type(8))) unsigned short u16x8;
typedef __attribute__((ext_vector_type(4))) float  f32x4;    // MFMA C/D frag

// tanh(x) = 1 - 2/(exp(2x)+1): NaN-free for any x, abs err ~1e-7.
__device__ __forceinline__ float tanh_fast(float x){
    const float e = __expf(2.0f * x);
    return 1.0f - 2.0f * __builtin_amdgcn_rcpf(e + 1.0f);
}
// bf16 split helpers: v ~= hi + lo
__device__ __forceinline__ unsigned short bhi(float v){
    return (unsigned short)(__float_as_uint(v) >> 16);
}
__device__ __forceinline__ unsigned short brne(float v){
    unsigned u = __float_as_uint(v);
    return (unsigned short)((u + 0x7FFFu + ((u >> 16) & 1u)) >> 16);
}
__device__ __forceinline__ float bf(unsigned short u){
    return __uint_as_float(((unsigned)u) << 16);
}
__device__ __forceinline__ unsigned pack_hl(float v){
    const unsigned short hi = bhi(v);
    const unsigned short lo = brne(v - bf(hi));
    return (((unsigned)hi) << 16) | (unsigned)lo;
}

// ---------------- prep: pack W1 (B/C orientations) + W0 into B-frag hi/lo --------
// ws layout (ushort): [0]=BhB [16384]=BlB [32768]=BhC [49152]=BlC
//                     [65536]=W0h(2048) [67584]=W0l(2048)
__global__ void prep_frags(const float* __restrict__ W1, const float* __restrict__ W0,
                           unsigned short* __restrict__ ws){
    const int t = blockIdx.x * 256 + threadIdx.x;
    if (t < 16384) {
        const int r = t & 7, l = (t >> 3) & 63, tile = t >> 9;
        const int nt = tile >> 2, ks = tile & 3;
        const int m = l >> 4, c = l & 15;
        const int k = ks * 32 + m * 8 + r;
        {
            const float v = W1[(nt * 16 + c) * HDIM + k];      // W1^T orientation (stage B)
            const unsigned short hi = bhi(v);
            ws[t]         = hi;
            ws[16384 + t] = brne(v - bf(hi));
        }
        {
            const float v = W1[k * HDIM + (nt * 16 + c)];      // W1 orientation (stage C)
            const unsigned short hi = bhi(v);
            ws[32768 + t] = hi;
            ws[49152 + t] = brne(v - bf(hi));
        }
    } else if (t < 18432) {
        const int t2 = t - 16384;                              // W0 B-frag (stage D)
        const int r = t2 & 7, l = (t2 >> 3) & 63, ks = t2 >> 9;
        const int m = l >> 4, c = l & 15;
        const int k = ks * 32 + m * 8 + r;
        const float v = (c < 8) ? W0[k * 8 + c] : 0.f;         // cols 8..15 zero
        const unsigned short hi = bhi(v);
        ws[65536 + t2] = hi;
        ws[67584 + t2] = brne(v - bf(hi));
    }
}

// ---------------- v11: S=32, wave-owned sample tiles, 2 barriers -----------------
// Wave w owns samples 8w..8w+7 end-to-end through stages A and B (stage A thread map
// s=tid>>3 produces exactly the act rows wave w's stage B reads; u1 overwrites only
// rows the same wave read) -> barriers before B and the v10 race-fix barrier both
// deleted. Stage B does all 128 j per wave (96 MFMA; 2x work per barrier interval).
// Remaining barriers: before C (u1/a0 cross-wave), before D (u0 cross-wave).
// xt dropped: force computed in stage A into fsm. LDS 53.1KB -> 3 blocks/CU.
__global__ __launch_bounds__(NT)
void dyn_mfma(const float* __restrict__ X, const float* __restrict__ Km,
              const float* __restrict__ Dm, const float* __restrict__ W0,
              const float* __restrict__ b0, const float* __restrict__ b1,
              const float* __restrict__ W2, const unsigned short* __restrict__ FR,
              float* __restrict__ out)
{
    __shared__ __align__(16) unsigned short act_hi[64 * ASTR];  // 17408 B
    __shared__ __align__(16) unsigned short act_lo[64 * ASTR];  // 17408 B
    __shared__ __align__(16) unsigned int   upk[32 * PSTR];     // 16896 B (a0 -> u0)
    __shared__ float fsm[S * 8];                                // 1024 B
    __shared__ float hvb[S];                                    // 128 B
    __shared__ float hvc[2][S];                                 // 256 B  -> 53120 B total

    const int tid = threadIdx.x;
    const long base = (long)blockIdx.x * S;

    const int wv = tid >> 6, l = tid & 63;
    const int m = l >> 4, c = l & 15;

    // ---------------- stage A: h0/dh0 -> act rows; a0 packed; force row ----------
    {
        const int s = tid >> 3;        // 0..31  (wave w -> samples 8w..8w+7)
        const int p = tid & 7;         // unit group: units p*16 .. p*16+15 ; force row d=p
        float xr[16];
        #pragma unroll
        for (int q = 0; q < 4; ++q)
            ((float4*)xr)[q] = ((const float4*)(X + (base + s) * 16))[q];
        // force f[s][p] = -(K[p].x + D[p].v)
        {
            const float4 ka = ((const float4*)Km)[p * 2], kb2 = ((const float4*)Km)[p * 2 + 1];
            const float4 da = ((const float4*)Dm)[p * 2], db2 = ((const float4*)Dm)[p * 2 + 1];
            float f = ka.x * xr[0];
            f = fmaf(ka.y, xr[1], f);  f = fmaf(ka.z, xr[2], f);  f = fmaf(ka.w, xr[3], f);
            f = fmaf(kb2.x, xr[4], f); f = fmaf(kb2.y, xr[5], f); f = fmaf(kb2.z, xr[6], f);
            f = fmaf(kb2.w, xr[7], f);
            f = fmaf(da.x, xr[8], f);  f = fmaf(da.y, xr[9], f);  f = fmaf(da.z, xr[10], f);
            f = fmaf(da.w, xr[11], f); f = fmaf(db2.x, xr[12], f); f = fmaf(db2.y, xr[13], f);
            f = fmaf(db2.z, xr[14], f); f = fmaf(db2.w, xr[15], f);
            fsm[s * 8 + p] = -f;
        }
        #pragma unroll
        for (int half = 0; half < 2; ++half) {
            const int kb = p * 16 + half * 8;                  // unit base
            float4 w0r[16];
            #pragma unroll
            for (int i = 0; i < 8; ++i) {
                w0r[2 * i]     = ((const float4*)W0)[(kb + i) * 2];
                w0r[2 * i + 1] = ((const float4*)W0)[(kb + i) * 2 + 1];
            }
            const float4 b0a = ((const float4*)b0)[kb >> 2];
            const float4 b0b = ((const float4*)b0)[(kb >> 2) + 1];
            const float bv[8] = {b0a.x, b0a.y, b0a.z, b0a.w, b0b.x, b0b.y, b0b.z, b0b.w};
            u16x8 hh, hl, dh_, dl;
            unsigned apk[8];
            #pragma unroll
            for (int i = 0; i < 8; ++i) {
                const float4 wa = w0r[2 * i];
                const float4 wb = w0r[2 * i + 1];
                float z = bv[i];
                z = fmaf(wa.x, xr[0], z); z = fmaf(wa.y, xr[1], z);
                z = fmaf(wa.z, xr[2], z); z = fmaf(wa.w, xr[3], z);
                z = fmaf(wb.x, xr[4], z); z = fmaf(wb.y, xr[5], z);
                z = fmaf(wb.z, xr[6], z); z = fmaf(wb.w, xr[7], z);
                float dz = wa.x * xr[8];
                dz = fmaf(wa.y, xr[9],  dz); dz = fmaf(wa.z, xr[10], dz); dz = fmaf(wa.w, xr[11], dz);
                dz = fmaf(wb.x, xr[12], dz); dz = fmaf(wb.y, xr[13], dz);
                dz = fmaf(wb.z, xr[14], dz); dz = fmaf(wb.w, xr[15], dz);
                const float h  = tanh_fast(z);
                const float e  = fmaf(-h, h, 1.0f);
                const float dh = e * dz;
                const float a0 = -2.f * h * e * dz * dz;
                hh[i]  = bhi(h);  hl[i] = brne(h  - bf(hh[i]));
                dh_[i] = bhi(dh); dl[i] = brne(dh - bf(dh_[i]));
                apk[i] = pack_hl(a0);
            }
            *(u16x8*)&act_hi[(2 * s)     * ASTR + kb] = hh;
            *(u16x8*)&act_lo[(2 * s)     * ASTR + kb] = hl;
            *(u16x8*)&act_hi[(2 * s + 1) * ASTR + kb] = dh_;
            *(u16x8*)&act_lo[(2 * s + 1) * ASTR + kb] = dl;
            *(uint4*)&upk[s * PSTR + kb]     = *(uint4*)&apk[0];
            *(uint4*)&upk[s * PSTR + kb + 4] = *(uint4*)&apk[4];
        }
    }
    // NO barrier: stage B reads only act rows 16wv..16wv+15 = this wave's own output
    // (same-wave DS ops complete in program order).

    // preload stage-B epilogue scalars (b1/W2 for all 8 j's of this lane)
    float b1v[8], w2v[8];
    #pragma unroll
    for (int n = 0; n < 8; ++n) {
        const int j = n * 16 + c;
        b1v[n] = b1[j];
        w2v[n] = W2[j];
    }

    // ---------------- stage B: [z1|dz1] = act(own tile) x W1^T, all 128 j --------
    const int mt = wv;                 // wave-owned m-tile
    f32x4 accB[8];
    #pragma unroll
    for (int n = 0; n < 8; ++n) accB[n] = (f32x4){0.f, 0.f, 0.f, 0.f};
    {
        const int arow = mt * 16 + c;
        bf16x8 ah[4], al[4];
        #pragma unroll
        for (int ks = 0; ks < 4; ++ks) {
            ah[ks] = *(const bf16x8*)&act_hi[arow * ASTR + ks * 32 + m * 8];
            al[ks] = *(const bf16x8*)&act_lo[arow * ASTR + ks * 32 + m * 8];
        }
        bf16x8 pbh[2][4], pbl[2][4];
        #pragma unroll
        for (int ks = 0; ks < 4; ++ks) {
            const int gi = ((0 * 4 + ks) * 64 + l) * 8;
            pbh[0][ks] = *(const bf16x8*)&FR[gi];
            pbl[0][ks] = *(const bf16x8*)&FR[16384 + gi];
        }
        #pragma unroll
        for (int n = 0; n < 8; ++n) {
            const int cur = n & 1;
            if (n < 7) {               // prefetch next n-tile (8 frags in flight)
                #pragma unroll
                for (int ks = 0; ks < 4; ++ks) {
                    const int gi = (((n + 1) * 4 + ks) * 64 + l) * 8;
                    pbh[cur ^ 1][ks] = *(const bf16x8*)&FR[gi];
                    pbl[cur ^ 1][ks] = *(const bf16x8*)&FR[16384 + gi];
                }
            }
            #pragma unroll
            for (int ks = 0; ks < 4; ++ks) {
                accB[n] = __builtin_amdgcn_mfma_f32_16x16x32_bf16(ah[ks], pbh[cur][ks], accB[n], 0, 0, 0);
                accB[n] = __builtin_amdgcn_mfma_f32_16x16x32_bf16(al[ks], pbh[cur][ks], accB[n], 0, 0, 0);
                accB[n] = __builtin_amdgcn_mfma_f32_16x16x32_bf16(ah[ks], pbl[cur][ks], accB[n], 0, 0, 0);
            }
        }
    }

    // ---- stage B epilogue: u1 -> own dh rows (wave-local, no barrier needed) ----
    {
        const int sA = mt * 8 + 2 * m, sB = sA + 1;            // global samples
        float hvA = 0.f, hvB = 0.f;
        #pragma unroll
        for (int n = 0; n < 8; ++n) {
            const int j = n * 16 + c;
            const float zA = accB[n][0] + b1v[n], dzA = accB[n][1];
            const float zB = accB[n][2] + b1v[n], dzB = accB[n][3];
            const float h1A = tanh_fast(zA), e1A = fmaf(-h1A, h1A, 1.f);
            const float u1A = w2v[n] * e1A;
            hvA = fmaf(-2.f * w2v[n] * h1A * e1A, dzA * dzA, hvA);
            const float h1B = tanh_fast(zB), e1B = fmaf(-h1B, h1B, 1.f);
            const float u1B = w2v[n] * e1B;
            hvB = fmaf(-2.f * w2v[n] * h1B * e1B, dzB * dzB, hvB);
            unsigned short uh = bhi(u1A);
            act_hi[(2 * sA + 1) * ASTR + j] = uh;              // own rows only
            act_lo[(2 * sA + 1) * ASTR + j] = brne(u1A - bf(uh));
            uh = bhi(u1B);
            act_hi[(2 * sB + 1) * ASTR + j] = uh;
            act_lo[(2 * sB + 1) * ASTR + j] = brne(u1B - bf(uh));
        }
        #pragma unroll
        for (int mk = 1; mk <= 8; mk <<= 1) {
            hvA += __shfl_xor(hvA, mk);
            hvB += __shfl_xor(hvB, mk);
        }
        if (c == 0) { hvb[sA] = hvA; hvb[sB] = hvB; }
    }

    // issue first stage-C FR tile before barrier 1 (FR-only deps)
    const int sm = wv >> 1, ih = wv & 1;   // stage C: sample half x i half
    bf16x8 cbh[2][4], cbl[2][4];
    #pragma unroll
    for (int ks = 0; ks < 4; ++ks) {
        const int gi = (((ih * 4 + 0) * 4 + ks) * 64 + l) * 8;
        cbh[0][ks] = *(const bf16x8*)&FR[32768 + gi];
        cbl[0][ks] = *(const bf16x8*)&FR[49152 + gi];
    }
    __syncthreads();   // barrier 1: u1 + a0 complete (cross-wave for stage C)

    // ---------------- stage C: t = u1 x W1 (16 samples x 64 i-cols per wave) -----
    f32x4 accC[4];
    #pragma unroll
    for (int n2 = 0; n2 < 4; ++n2) accC[n2] = (f32x4){0.f, 0.f, 0.f, 0.f};
    {
        const int urow = 2 * (sm * 16 + c) + 1;                // u1 row of sample sm*16+c
        bf16x8 uh4[4], ul4[4];
        #pragma unroll
        for (int ks = 0; ks < 4; ++ks) {
            uh4[ks] = *(const bf16x8*)&act_hi[urow * ASTR + ks * 32 + m * 8];
            ul4[ks] = *(const bf16x8*)&act_lo[urow * ASTR + ks * 32 + m * 8];
        }
        #pragma unroll
        for (int n2 = 0; n2 < 4; ++n2) {
            const int cur = n2 & 1;
            if (n2 < 3) {
                #pragma unroll
                for (int ks = 0; ks < 4; ++ks) {
                    const int gi = (((ih * 4 + n2 + 1) * 4 + ks) * 64 + l) * 8;
                    cbh[cur ^ 1][ks] = *(const bf16x8*)&FR[32768 + gi];
                    cbl[cur ^ 1][ks] = *(const bf16x8*)&FR[49152 + gi];
                }
            }
            #pragma unroll
            for (int ks = 0; ks < 4; ++ks) {
                accC[n2] = __builtin_amdgcn_mfma_f32_16x16x32_bf16(uh4[ks], cbh[cur][ks], accC[n2], 0, 0, 0);
                accC[n2] = __builtin_amdgcn_mfma_f32_16x16x32_bf16(ul4[ks], cbh[cur][ks], accC[n2], 0, 0, 0);
                accC[n2] = __builtin_amdgcn_mfma_f32_16x16x32_bf16(uh4[ks], cbl[cur][ks], accC[n2], 0, 0, 0);
            }
        }
    }

    // ---- stage C epilogue: hvv1 += a0.t ; u0 = e0*t packed, overwrites upk ------
    {
        float hv1[4] = {0.f, 0.f, 0.f, 0.f};
        #pragma unroll
        for (int n2 = 0; n2 < 4; ++n2) {
            const int i = ih * 64 + n2 * 16 + c;
            #pragma unroll
            for (int p = 0; p < 4; ++p) {
                const int s = sm * 16 + 4 * m + p;             // D row -> sample
                const float tv = accC[n2][p];
                const float h0 = bf(act_hi[(2 * s) * ASTR + i]) + bf(act_lo[(2 * s) * ASTR + i]);
                const unsigned apk = upk[s * PSTR + i];
                const float a0 = __uint_as_float(apk & 0xFFFF0000u)
                               + __uint_as_float(apk << 16);
                const float e0 = fmaf(-h0, h0, 1.f);
                const float u0 = e0 * tv;
                hv1[p] = fmaf(a0, tv, hv1[p]);
                upk[s * PSTR + i] = pack_hl(u0);               // same-lane RMW, unique (s,i) owner
            }
        }
        #pragma unroll
        for (int mk = 1; mk <= 8; mk <<= 1) {
            #pragma unroll
            for (int p = 0; p < 4; ++p) hv1[p] += __shfl_xor(hv1[p], mk);
        }
        if (c == 0) {
            #pragma unroll
            for (int p = 0; p < 4; ++p) hvc[ih][sm * 16 + 4 * m + p] = hv1[p];
        }
    }

    // issue stage-D FR frags before barrier 2 (waves 0,1 use them)
    bf16x8 dbh[4], dbl[4];
    if (wv < 2) {
        #pragma unroll
        for (int ks = 0; ks < 4; ++ks) {
            const int gi = (ks * 64 + l) * 8;
            dbh[ks] = *(const bf16x8*)&FR[65536 + gi];
            dbl[ks] = *(const bf16x8*)&FR[67584 + gi];
        }
    }
    __syncthreads();   // barrier 2 (last): u0/hv/fsm complete

    if (wv >= 2) return;   // waves 2,3 done; waves 0,1 finish 16 samples each

    // ---------------- stage D: g = u0 x W0 (3-pass hi/lo MFMA) -------------------
    const int smD = wv;                // sample half
    f32x4 accG = (f32x4){0.f, 0.f, 0.f, 0.f};
    #pragma unroll
    for (int ks = 0; ks < 4; ++ks) {
        unsigned u[8];
        *(uint4*)&u[0] = *(const uint4*)&upk[(smD * 16 + c) * PSTR + ks * 32 + m * 8];
        *(uint4*)&u[4] = *(const uint4*)&upk[(smD * 16 + c) * PSTR + ks * 32 + m * 8 + 4];
        bf16x8 ah, al;
        #pragma unroll
        for (int j = 0; j < 8; ++j) {
            ah[j] = (short)(u[j] >> 16);
            al[j] = (short)(u[j] & 0xFFFFu);
        }
        accG = __builtin_amdgcn_mfma_f32_16x16x32_bf16(ah, dbh[ks], accG, 0, 0, 0);
        accG = __builtin_amdgcn_mfma_f32_16x16x32_bf16(al, dbh[ks], accG, 0, 0, 0);
        accG = __builtin_amdgcn_mfma_f32_16x16x32_bf16(ah, dbl[ks], accG, 0, 0, 0);
    }

    // ---------------- tail: alpha, output (force from fsm) -----------------------
    {
        #pragma unroll
        for (int p = 0; p < 4; ++p) {
            const int s = smD * 16 + 4 * m + p;
            const float g = accG[p];                            // g[s][c] (c<8; else 0)
            const float hvv = hvb[s] + hvc[0][s] + hvc[1][s];
            const float f = fsm[s * 8 + (c & 7)];
            float pgf = g * f, pgg = g * g;                     // c>=8 lanes contribute 0
            #pragma unroll
            for (int mk = 1; mk <= 8; mk <<= 1) {
                pgf += __shfl_xor(pgf, mk);
                pgg += __shfl_xor(pgg, mk);
            }
            const float al_ = (pgf + hvv) * __builtin_amdgcn_rcpf(1.f + pgg);
            if (c < 8)
                out[(base + s) * 8 + c] = fmaf(-g, al_, f);
        }
    }
}

// ---------------- correct (slow) fallback if workspace too small -----------------
__global__ void dyn_naive(const float* __restrict__ X, const float* __restrict__ Km,
                          const float* __restrict__ Dm, const float* __restrict__ W0,
                          const float* __restrict__ b0, const float* __restrict__ W1,
                          const float* __restrict__ b1, const float* __restrict__ W2,
                          float* __restrict__ out)
{
    const long sidx = (long)blockIdx.x * 64 + threadIdx.x;
    const float* xv = X + sidx * 16;
    float h0[HDIM], dh0[HDIM], a0[HDIM], u1[HDIM];
    for (int k = 0; k < HDIM; ++k) {
        float z = b0[k], dz = 0.f;
        for (int d = 0; d < 8; ++d) { z = fmaf(W0[k*8+d], xv[d], z); dz = fmaf(W0[k*8+d], xv[8+d], dz); }
        const float h = tanhf(z), e = 1.f - h*h;
        h0[k] = h; dh0[k] = e*dz; a0[k] = -2.f*h*e*dz*dz;
    }
    float hvv = 0.f;
    for (int j = 0; j < HDIM; ++j) {
        float z = b1[j], dz = 0.f, cc = 0.f;
        for (int k = 0; k < HDIM; ++k) {
            const float w = W1[j*HDIM+k];
            z = fmaf(w, h0[k], z); dz = fmaf(w, dh0[k], dz); cc = fmaf(w, a0[k], cc);
        }
        const float h = tanhf(z), e = 1.f - h*h;
        u1[j] = W2[j]*e;
        hvv += W2[j]*(e*cc - 2.f*h*e*dz*dz);
    }
    float g[8] = {0,0,0,0,0,0,0,0};
    for (int k = 0; k < HDIM; ++k) {
        float t = 0.f;
        for (int j = 0; j < HDIM; ++j) t = fmaf(u1[j], W1[j*HDIM+k], t);
        const float u0 = (1.f - h0[k]*h0[k]) * t;
        for (int d = 0; d < 8; ++d) g[d] = fmaf(W0[k*8+d], u0, g[d]);
    }
    float fd[8], gf = 0.f, gg = 0.f;
    for (int d = 0; d < 8; ++d) {
        float a = 0.f;
        for (int k = 0; k < 8; ++k) { a = fmaf(Km[d*8+k], xv[k], a); a = fmaf(Dm[d*8+k], xv[8+k], a); }
        fd[d] = -a; gf = fmaf(g[d], fd[d], gf); gg = fmaf(g[d], g[d], gg);
    }
    const float al = (gf + hvv) / (1.f + gg);
    for (int d = 0; d < 8; ++d) out[sidx*8 + d] = fd[d] - g[d]*al;
}

extern "C" void kernel_launch(void* const* d_in, const int* in_sizes, int n_in,
                              void* d_out, int out_size, void* d_ws, size_t ws_size,
                              hipStream_t stream) {
    const float* X  = (const float*)d_in[0];
    const float* Km = (const float*)d_in[1];
    const float* Dm = (const float*)d_in[2];
    const float* W0 = (const float*)d_in[3];
    const float* b0 = (const float*)d_in[4];
    const float* W1 = (const float*)d_in[5];
    const float* b1 = (const float*)d_in[6];
    const float* W2 = (const float*)d_in[7];
    // d_in[8] = b2 (unused: cancels in grad/hessian/force)
    float* out = (float*)d_out;

    const int BATCH = in_sizes[0] / 16;        // 65536
    if (ws_size >= (size_t)(69632 * sizeof(unsigned short))) {   // 136 KiB
        unsigned short* FR = (unsigned short*)d_ws;
        prep_frags<<<72, 256, 0, stream>>>(W1, W0, FR);
        dyn_mfma<<<BATCH / S, NT, 0, stream>>>(X, Km, Dm, W0, b0, b1, W2, FR, out);
    } else {
        dyn_naive<<<BATCH / 64, 64, 0, stream>>>(X, Km, Dm, W0, b0, W1, b1, W2, out);
    }
}

// Round 11
// 111.729 us; speedup vs baseline: 1.2315x; 1.2315x over previous
//
#include <hip/hip_runtime.h>
#include <math.h>

#define HDIM 128
#define S 16            // samples per workgroup
#define NT 256
#define ASTR 136        // bf16 row stride (ushort)
#define PSTR 132        // u32 row stride

typedef __attribute__((ext_vector_type(8))) short  bf16x8;   // MFMA A/B frag
typedef __attribute__((ext_vector_type(8))) unsigned short u16x8;
typedef __attribute__((ext_vector_type(4))) float  f32x4;    // MFMA C/D frag

// tanh(x) = 1 - 2/(exp(2x)+1): NaN-free for any x, abs err ~1e-7.
__device__ __forceinline__ float tanh_fast(float x){
    const float e = __expf(2.0f * x);
    return 1.0f - 2.0f * __builtin_amdgcn_rcpf(e + 1.0f);
}
// bf16 split helpers: v ~= hi + lo
__device__ __forceinline__ unsigned short bhi(float v){
    return (unsigned short)(__float_as_uint(v) >> 16);
}
__device__ __forceinline__ unsigned short brne(float v){
    unsigned u = __float_as_uint(v);
    return (unsigned short)((u + 0x7FFFu + ((u >> 16) & 1u)) >> 16);
}
__device__ __forceinline__ float bf(unsigned short u){
    return __uint_as_float(((unsigned)u) << 16);
}
__device__ __forceinline__ unsigned pack_hl(float v){
    const unsigned short hi = bhi(v);
    const unsigned short lo = brne(v - bf(hi));
    return (((unsigned)hi) << 16) | (unsigned)lo;
}

// ---------------- prep: pack weights into B-fragment order, hi/lo bf16 -----------
// ws layout (ushort): [0]=BhB(W1^T) [16384]=BlB [32768]=BhC(W1) [49152]=BlC
//                     [65536]=W0h stage-D (2048) [67584]=W0l (2048)
//                     [69632]=Ah stage-A (W0^T + bias k-slot, 4096) [73728]=Al (4096)
__global__ void prep_frags(const float* __restrict__ W1, const float* __restrict__ W0,
                           const float* __restrict__ b0, unsigned short* __restrict__ ws){
    const int t = blockIdx.x * 256 + threadIdx.x;
    if (t < 16384) {
        const int r = t & 7, l = (t >> 3) & 63, tile = t >> 9;
        const int nt = tile >> 2, ks = tile & 3;
        const int m = l >> 4, c = l & 15;
        const int k = ks * 32 + m * 8 + r;
        {
            const float v = W1[(nt * 16 + c) * HDIM + k];      // W1^T orientation (stage B)
            const unsigned short hi = bhi(v);
            ws[t]         = hi;
            ws[16384 + t] = brne(v - bf(hi));
        }
        {
            const float v = W1[k * HDIM + (nt * 16 + c)];      // W1 orientation (stage C)
            const unsigned short hi = bhi(v);
            ws[32768 + t] = hi;
            ws[49152 + t] = brne(v - bf(hi));
        }
    } else if (t < 18432) {
        const int t2 = t - 16384;                              // W0 B-frag (stage D)
        const int r = t2 & 7, l = (t2 >> 3) & 63, ks = t2 >> 9;
        const int m = l >> 4, c = l & 15;
        const int k = ks * 32 + m * 8 + r;
        const float v = (c < 8) ? W0[k * 8 + c] : 0.f;         // cols 8..15 zero
        const unsigned short hi = bhi(v);
        ws[65536 + t2] = hi;
        ws[67584 + t2] = brne(v - bf(hi));
    } else if (t < 22528) {
        const int t3 = t - 18432;                              // stage-A B-frag: W0^T + bias
        const int r = t3 & 7, l = (t3 >> 3) & 63, nt = t3 >> 9;   // nt 0..7, ks=0 only
        const int m = l >> 4, c = l & 15;
        const int k = m * 8 + r;                               // 0..31
        const int j = nt * 16 + c;
        float v = 0.f;
        if (k < 8)       v = W0[j * 8 + k];
        else if (k == 8) v = b0[j];                            // bias k-slot
        const unsigned short hi = bhi(v);
        ws[69632 + t3] = hi;
        ws[73728 + t3] = brne(v - bf(hi));
    }
}

// ---------------- v12: stage A on MFMA too; a0 raw fp32; 5 blocks/CU -------------
// v11's 53KB LDS dropped co-residency 5->3 blocks/CU and lost 6% — reverted to S=16.
// New: stage A's z/dz GEMV moved to MFMA (A rows interleaved x/v, K=8 + bias k-slot
// A[x-row][8]=1, B[8][j]=b0[j] -> z biased, dz not, free). 12 MFMA/wave replace
// 256 fma/thread. a0 stored as raw fp32 in upk (never an MFMA operand - no packing).
// Barriers: 5 (X-stage, act-ready, race-fix, u1-ready, u0-ready).
__global__ __launch_bounds__(NT)
void dyn_mfma(const float* __restrict__ X, const float* __restrict__ Km,
              const float* __restrict__ Dm, const float* __restrict__ b1,
              const float* __restrict__ W2, const unsigned short* __restrict__ FR,
              float* __restrict__ out)
{
    __shared__ __align__(16) unsigned short act_hi[32 * ASTR];  // 8704 B
    __shared__ __align__(16) unsigned short act_lo[32 * ASTR];  // 8704 B
    __shared__ __align__(16) unsigned int   upk[16 * PSTR];     // 8448 B (a0 f32 -> u0 packed)
    __shared__ __align__(16) unsigned short xa_hi[256];         // 512 B (A rows: 2s=x, 2s+1=v)
    __shared__ __align__(16) unsigned short xa_lo[256];         // 512 B
    __shared__ float xt[S * 16];                                // 1 KB (fp32, force)
    __shared__ float hvb[2][16];
    __shared__ float hvc[4][16];                                // -> 28.3 KB total

    const int tid = threadIdx.x;
    const long base = (long)blockIdx.x * S;

    const int wv = tid >> 6, l = tid & 63;
    const int m = l >> 4, c = l & 15;
    const int mt = wv >> 1, nh = wv & 1;   // m-tile (8 samples) x n-half

    // ---------------- pre-stage: X -> xt (f32) + xa (bf16 hi/lo, interleaved) ----
    {
        // linear: thread t handles X[base*16 + t]; xa row 2s+(e>=8), col e&7 == index t
        const float xv = X[base * 16 + tid];
        xt[tid] = xv;
        const unsigned short xh = bhi(xv);
        xa_hi[tid] = xh;
        xa_lo[tid] = brne(xv - bf(xh));
    }

    // preload stage-A B-frags (FR-only deps; hide under barrier)
    bf16x8 afh[4], afl[4];
    #pragma unroll
    for (int n = 0; n < 4; ++n) {
        const int gi = (((nh * 4 + n) * 64) + l) * 8;
        afh[n] = *(const bf16x8*)&FR[69632 + gi];
        afl[n] = *(const bf16x8*)&FR[73728 + gi];
    }
    __syncthreads();   // barrier 0: xa/xt ready

    // ---------------- stage A: [z|dz] = xa x (W0^T + bias) via MFMA --------------
    f32x4 accA[4];
    #pragma unroll
    for (int n = 0; n < 4; ++n) accA[n] = (f32x4){0.f, 0.f, 0.f, 0.f};
    {
        bf16x8 axh = {0,0,0,0,0,0,0,0}, axl = {0,0,0,0,0,0,0,0};
        if (m == 0) {                  // k=0..7: x (even rows) / v (odd rows)
            axh = *(const bf16x8*)&xa_hi[(mt * 16 + c) * 8];
            axl = *(const bf16x8*)&xa_lo[(mt * 16 + c) * 8];
        } else if (m == 1) {           // k=8 bias slot: 1.0 on x-rows only
            axh[0] = (short)(((c & 1) == 0) ? 0x3F80 : 0);
        }
        #pragma unroll
        for (int n = 0; n < 4; ++n) {
            accA[n] = __builtin_amdgcn_mfma_f32_16x16x32_bf16(axh, afh[n], accA[n], 0, 0, 0);
            accA[n] = __builtin_amdgcn_mfma_f32_16x16x32_bf16(axl, afh[n], accA[n], 0, 0, 0);
            accA[n] = __builtin_amdgcn_mfma_f32_16x16x32_bf16(axh, afl[n], accA[n], 0, 0, 0);
        }
    }

    // ---- stage A epilogue: h/dh -> act rows (bf16 hi/lo); a0 -> upk (raw f32) ---
    #pragma unroll
    for (int n = 0; n < 4; ++n) {
        const int j = (nh * 4 + n) * 16 + c;
        #pragma unroll
        for (int pr = 0; pr < 2; ++pr) {
            const int s = mt * 8 + 2 * m + pr;
            const float z  = accA[n][2 * pr];       // bias already included
            const float dz = accA[n][2 * pr + 1];
            const float h  = tanh_fast(z);
            const float e  = fmaf(-h, h, 1.f);
            const float dh = e * dz;
            const float a0 = -2.f * h * dh * dz;
            unsigned short t16 = bhi(h);
            act_hi[(2 * s) * ASTR + j] = t16;
            act_lo[(2 * s) * ASTR + j] = brne(h - bf(t16));
            t16 = bhi(dh);
            act_hi[(2 * s + 1) * ASTR + j] = t16;
            act_lo[(2 * s + 1) * ASTR + j] = brne(dh - bf(t16));
            upk[s * PSTR + j] = __float_as_uint(a0);
        }
    }

    // issue FIRST stage-B FR tile + epilogue scalars before the barrier
    bf16x8 pbh[2][4], pbl[2][4];
    #pragma unroll
    for (int ks = 0; ks < 4; ++ks) {
        const int gi = (((nh * 4 + 0) * 4 + ks) * 64 + l) * 8;
        pbh[0][ks] = *(const bf16x8*)&FR[gi];
        pbl[0][ks] = *(const bf16x8*)&FR[16384 + gi];
    }
    float b1v[4], w2v[4];
    #pragma unroll
    for (int n = 0; n < 4; ++n) {
        const int j = (nh * 4 + n) * 16 + c;
        b1v[n] = b1[j];
        w2v[n] = W2[j];
    }
    __syncthreads();   // barrier 1: act/a0 complete (cross-wave)

    // ---------------- stage B: [z1|dz1] = act x W1^T (3-pass hi/lo MFMA) ---------
    f32x4 accB[4];
    #pragma unroll
    for (int n = 0; n < 4; ++n) accB[n] = (f32x4){0.f, 0.f, 0.f, 0.f};
    {
        const int arow = mt * 16 + c;
        bf16x8 ah[4], al[4];
        #pragma unroll
        for (int ks = 0; ks < 4; ++ks) {
            ah[ks] = *(const bf16x8*)&act_hi[arow * ASTR + ks * 32 + m * 8];
            al[ks] = *(const bf16x8*)&act_lo[arow * ASTR + ks * 32 + m * 8];
        }
        #pragma unroll
        for (int n = 0; n < 4; ++n) {
            const int cur = n & 1;
            if (n < 3) {               // prefetch next n-tile
                #pragma unroll
                for (int ks = 0; ks < 4; ++ks) {
                    const int gi = (((nh * 4 + n + 1) * 4 + ks) * 64 + l) * 8;
                    pbh[cur ^ 1][ks] = *(const bf16x8*)&FR[gi];
                    pbl[cur ^ 1][ks] = *(const bf16x8*)&FR[16384 + gi];
                }
            }
            #pragma unroll
            for (int ks = 0; ks < 4; ++ks) {
                accB[n] = __builtin_amdgcn_mfma_f32_16x16x32_bf16(ah[ks], pbh[cur][ks], accB[n], 0, 0, 0);
                accB[n] = __builtin_amdgcn_mfma_f32_16x16x32_bf16(al[ks], pbh[cur][ks], accB[n], 0, 0, 0);
                accB[n] = __builtin_amdgcn_mfma_f32_16x16x32_bf16(ah[ks], pbl[cur][ks], accB[n], 0, 0, 0);
            }
        }
    }

    // ---- stage B epilogue, part 1: u1/hvv into REGISTERS only -------------------
    const int sA = mt * 8 + 2 * m, sB = sA + 1;
    float u1Av[4], u1Bv[4];
    float hvA = 0.f, hvB = 0.f;
    #pragma unroll
    for (int n = 0; n < 4; ++n) {
        const float zA = accB[n][0] + b1v[n], dzA = accB[n][1];
        const float zB = accB[n][2] + b1v[n], dzB = accB[n][3];
        const float h1A = tanh_fast(zA), e1A = fmaf(-h1A, h1A, 1.f);
        u1Av[n] = w2v[n] * e1A;
        hvA = fmaf(-2.f * w2v[n] * h1A * e1A, dzA * dzA, hvA);
        const float h1B = tanh_fast(zB), e1B = fmaf(-h1B, h1B, 1.f);
        u1Bv[n] = w2v[n] * e1B;
        hvB = fmaf(-2.f * w2v[n] * h1B * e1B, dzB * dzB, hvB);
    }
    #pragma unroll
    for (int mk = 1; mk <= 8; mk <<= 1) {
        hvA += __shfl_xor(hvA, mk);
        hvB += __shfl_xor(hvB, mk);
    }

    // issue ALL stage-C FR frags before the barriers (latency hides here)
    bf16x8 cbh[2][4], cbl[2][4];
    #pragma unroll
    for (int n2 = 0; n2 < 2; ++n2)
        #pragma unroll
        for (int ks = 0; ks < 4; ++ks) {
            const int gi = (((wv * 2 + n2) * 4 + ks) * 64 + l) * 8;
            cbh[n2][ks] = *(const bf16x8*)&FR[32768 + gi];
            cbl[n2][ks] = *(const bf16x8*)&FR[49152 + gi];
        }

    __syncthreads();   // barrier 2 (race fix): all waves done READING dh rows

    // ---- stage B epilogue, part 2: store u1 over the dead dh rows ---------------
    #pragma unroll
    for (int n = 0; n < 4; ++n) {
        const int j = (nh * 4 + n) * 16 + c;
        unsigned short uh = bhi(u1Av[n]);
        act_hi[(2 * sA + 1) * ASTR + j] = uh;
        act_lo[(2 * sA + 1) * ASTR + j] = brne(u1Av[n] - bf(uh));
        uh = bhi(u1Bv[n]);
        act_hi[(2 * sB + 1) * ASTR + j] = uh;
        act_lo[(2 * sB + 1) * ASTR + j] = brne(u1Bv[n] - bf(uh));
    }
    if (c == 0) { hvb[nh][sA] = hvA; hvb[nh][sB] = hvB; }
    __syncthreads();   // barrier 3: u1 complete

    // ---------------- stage C: t = u1 x W1 (3-pass hi/lo MFMA) -------------------
    f32x4 accC[2];
    accC[0] = (f32x4){0.f, 0.f, 0.f, 0.f};
    accC[1] = (f32x4){0.f, 0.f, 0.f, 0.f};
    {
        const int urow = 2 * c + 1;                             // u1 row of sample c
        bf16x8 uh4[4], ul4[4];
        #pragma unroll
        for (int ks = 0; ks < 4; ++ks) {
            uh4[ks] = *(const bf16x8*)&act_hi[urow * ASTR + ks * 32 + m * 8];
            ul4[ks] = *(const bf16x8*)&act_lo[urow * ASTR + ks * 32 + m * 8];
        }
        #pragma unroll
        for (int n2 = 0; n2 < 2; ++n2)
            #pragma unroll
            for (int ks = 0; ks < 4; ++ks) {
                accC[n2] = __builtin_amdgcn_mfma_f32_16x16x32_bf16(uh4[ks], cbh[n2][ks], accC[n2], 0, 0, 0);
                accC[n2] = __builtin_amdgcn_mfma_f32_16x16x32_bf16(ul4[ks], cbh[n2][ks], accC[n2], 0, 0, 0);
                accC[n2] = __builtin_amdgcn_mfma_f32_16x16x32_bf16(uh4[ks], cbl[n2][ks], accC[n2], 0, 0, 0);
            }
    }

    // ---- stage C epilogue: hvv1 += a0.t ; u0 = e0*t packed, overwrites upk ------
    {
        float hv1[4] = {0.f, 0.f, 0.f, 0.f};
        #pragma unroll
        for (int n2 = 0; n2 < 2; ++n2) {
            const int i = (wv * 2 + n2) * 16 + c;
            #pragma unroll
            for (int p = 0; p < 4; ++p) {
                const int s = 4 * m + p;                        // D row -> sample
                const float tv = accC[n2][p];
                const float h0 = bf(act_hi[(2 * s) * ASTR + i]) + bf(act_lo[(2 * s) * ASTR + i]);
                const float a0 = __uint_as_float(upk[s * PSTR + i]);   // raw fp32
                const float e0 = fmaf(-h0, h0, 1.f);
                const float u0 = e0 * tv;
                hv1[p] = fmaf(a0, tv, hv1[p]);
                upk[s * PSTR + i] = pack_hl(u0);                // same-lane RMW, no race
            }
        }
        #pragma unroll
        for (int mk = 1; mk <= 8; mk <<= 1) {
            #pragma unroll
            for (int p = 0; p < 4; ++p) hv1[p] += __shfl_xor(hv1[p], mk);
        }
        if (c == 0) {
            #pragma unroll
            for (int p = 0; p < 4; ++p) hvc[wv][4 * m + p] = hv1[p];
        }
    }

    // issue stage-D FR frags + K/D rows before barrier 4 (wave 0 only uses them)
    bf16x8 dbh[4], dbl[4];
    float4 ka, kb, da, db;
    if (wv == 0) {
        #pragma unroll
        for (int ks = 0; ks < 4; ++ks) {
            const int gi = (ks * 64 + l) * 8;
            dbh[ks] = *(const bf16x8*)&FR[65536 + gi];
            dbl[ks] = *(const bf16x8*)&FR[67584 + gi];
        }
        const int dd = c & 7;
        ka = ((const float4*)Km)[dd * 2]; kb = ((const float4*)Km)[dd * 2 + 1];
        da = ((const float4*)Dm)[dd * 2]; db = ((const float4*)Dm)[dd * 2 + 1];
    }
    __syncthreads();   // barrier 4 (last): u0/hv complete

    if (wv != 0) return;   // waves 1-3 done; wave 0 finishes the block

    // ---------------- stage D (wave 0): g = u0 x W0 (3-pass hi/lo MFMA) ----------
    f32x4 accG = (f32x4){0.f, 0.f, 0.f, 0.f};
    #pragma unroll
    for (int ks = 0; ks < 4; ++ks) {
        unsigned u[8];
        *(uint4*)&u[0] = *(const uint4*)&upk[c * PSTR + ks * 32 + m * 8];
        *(uint4*)&u[4] = *(const uint4*)&upk[c * PSTR + ks * 32 + m * 8 + 4];
        bf16x8 ah, al;
        #pragma unroll
        for (int j = 0; j < 8; ++j) {
            ah[j] = (short)(u[j] >> 16);
            al[j] = (short)(u[j] & 0xFFFFu);
        }
        accG = __builtin_amdgcn_mfma_f32_16x16x32_bf16(ah, dbh[ks], accG, 0, 0, 0);
        accG = __builtin_amdgcn_mfma_f32_16x16x32_bf16(al, dbh[ks], accG, 0, 0, 0);
        accG = __builtin_amdgcn_mfma_f32_16x16x32_bf16(ah, dbl[ks], accG, 0, 0, 0);
    }

    // ---------------- tail (wave 0): force, alpha, output ------------------------
    {
        #pragma unroll
        for (int p = 0; p < 4; ++p) {
            const int s = 4 * m + p;
            const float g = accG[p];                            // g[s][c] (c<8; else 0)
            const float hvv = hvb[0][s] + hvb[1][s]
                            + hvc[0][s] + hvc[1][s] + hvc[2][s] + hvc[3][s];
            const float* xv = &xt[s * 16];
            float f = ka.x * xv[0];
            f = fmaf(ka.y, xv[1], f);  f = fmaf(ka.z, xv[2], f);  f = fmaf(ka.w, xv[3], f);
            f = fmaf(kb.x, xv[4], f);  f = fmaf(kb.y, xv[5], f);  f = fmaf(kb.z, xv[6], f);
            f = fmaf(kb.w, xv[7], f);
            f = fmaf(da.x, xv[8], f);  f = fmaf(da.y, xv[9], f);  f = fmaf(da.z, xv[10], f);
            f = fmaf(da.w, xv[11], f); f = fmaf(db.x, xv[12], f); f = fmaf(db.y, xv[13], f);
            f = fmaf(db.z, xv[14], f); f = fmaf(db.w, xv[15], f);
            f = -f;
            float pgf = g * f, pgg = g * g;                     // c>=8 lanes contribute 0
            #pragma unroll
            for (int mk = 1; mk <= 8; mk <<= 1) {
                pgf += __shfl_xor(pgf, mk);
                pgg += __shfl_xor(pgg, mk);
            }
            const float al_ = (pgf + hvv) * __builtin_amdgcn_rcpf(1.f + pgg);
            if (c < 8)
                out[(base + s) * 8 + c] = fmaf(-g, al_, f);
        }
    }
}

// ---------------- correct (slow) fallback if workspace too small -----------------
__global__ void dyn_naive(const float* __restrict__ X, const float* __restrict__ Km,
                          const float* __restrict__ Dm, const float* __restrict__ W0,
                          const float* __restrict__ b0, const float* __restrict__ W1,
                          const float* __restrict__ b1, const float* __restrict__ W2,
                          float* __restrict__ out)
{
    const long sidx = (long)blockIdx.x * 64 + threadIdx.x;
    const float* xv = X + sidx * 16;
    float h0[HDIM], dh0[HDIM], a0[HDIM], u1[HDIM];
    for (int k = 0; k < HDIM; ++k) {
        float z = b0[k], dz = 0.f;
        for (int d = 0; d < 8; ++d) { z = fmaf(W0[k*8+d], xv[d], z); dz = fmaf(W0[k*8+d], xv[8+d], dz); }
        const float h = tanhf(z), e = 1.f - h*h;
        h0[k] = h; dh0[k] = e*dz; a0[k] = -2.f*h*e*dz*dz;
    }
    float hvv = 0.f;
    for (int j = 0; j < HDIM; ++j) {
        float z = b1[j], dz = 0.f, cc = 0.f;
        for (int k = 0; k < HDIM; ++k) {
            const float w = W1[j*HDIM+k];
            z = fmaf(w, h0[k], z); dz = fmaf(w, dh0[k], dz); cc = fmaf(w, a0[k], cc);
        }
        const float h = tanhf(z), e = 1.f - h*h;
        u1[j] = W2[j]*e;
        hvv += W2[j]*(e*cc - 2.f*h*e*dz*dz);
    }
    float g[8] = {0,0,0,0,0,0,0,0};
    for (int k = 0; k < HDIM; ++k) {
        float t = 0.f;
        for (int j = 0; j < HDIM; ++j) t = fmaf(u1[j], W1[j*HDIM+k], t);
        const float u0 = (1.f - h0[k]*h0[k]) * t;
        for (int d = 0; d < 8; ++d) g[d] = fmaf(W0[k*8+d], u0, g[d]);
    }
    float fd[8], gf = 0.f, gg = 0.f;
    for (int d = 0; d < 8; ++d) {
        float a = 0.f;
        for (int k = 0; k < 8; ++k) { a = fmaf(Km[d*8+k], xv[k], a); a = fmaf(Dm[d*8+k], xv[8+k], a); }
        fd[d] = -a; gf = fmaf(g[d], fd[d], gf); gg = fmaf(g[d], g[d], gg);
    }
    const float al = (gf + hvv) / (1.f + gg);
    for (int d = 0; d < 8; ++d) out[sidx*8 + d] = fd[d] - g[d]*al;
}

extern "C" void kernel_launch(void* const* d_in, const int* in_sizes, int n_in,
                              void* d_out, int out_size, void* d_ws, size_t ws_size,
                              hipStream_t stream) {
    const float* X  = (const float*)d_in[0];
    const float* Km = (const float*)d_in[1];
    const float* Dm = (const float*)d_in[2];
    const float* W0 = (const float*)d_in[3];
    const float* b0 = (const float*)d_in[4];
    const float* W1 = (const float*)d_in[5];
    const float* b1 = (const float*)d_in[6];
    const float* W2 = (const float*)d_in[7];
    // d_in[8] = b2 (unused: cancels in grad/hessian/force)
    float* out = (float*)d_out;

    const int BATCH = in_sizes[0] / 16;        // 65536
    if (ws_size >= (size_t)(77824 * sizeof(unsigned short))) {   // 152 KiB
        unsigned short* FR = (unsigned short*)d_ws;
        prep_frags<<<88, 256, 0, stream>>>(W1, W0, b0, FR);
        dyn_mfma<<<BATCH / S, NT, 0, stream>>>(X, Km, Dm, b1, W2, FR, out);
    } else {
        dyn_naive<<<BATCH / 64, 64, 0, stream>>>(X, Km, Dm, W0, b0, W1, b1, W2, out);
    }
}

// Round 12
// 100.092 us; speedup vs baseline: 1.3746x; 1.1163x over previous
//
#include <hip/hip_runtime.h>
#include <math.h>

#define HDIM 128
#define S 16            // samples per workgroup
#define NT 256
#define ASTR 136        // bf16 row stride (ushort)
#define PSTR 132        // u32 row stride

typedef __attribute__((ext_vector_type(8))) short  bf16x8;   // MFMA A/B frag
typedef __attribute__((ext_vector_type(8))) unsigned short u16x8;
typedef __attribute__((ext_vector_type(4))) float  f32x4;    // MFMA C/D frag

// tanh(x) = 1 - 2/(exp(2x)+1): NaN-free for any x, abs err ~1e-7.
__device__ __forceinline__ float tanh_fast(float x){
    const float e = __expf(2.0f * x);
    return 1.0f - 2.0f * __builtin_amdgcn_rcpf(e + 1.0f);
}
// bf16 split helpers: v ~= hi + lo
__device__ __forceinline__ unsigned short bhi(float v){
    return (unsigned short)(__float_as_uint(v) >> 16);
}
__device__ __forceinline__ unsigned short brne(float v){
    unsigned u = __float_as_uint(v);
    return (unsigned short)((u + 0x7FFFu + ((u >> 16) & 1u)) >> 16);
}
__device__ __forceinline__ float bf(unsigned short u){
    return __uint_as_float(((unsigned)u) << 16);
}
__device__ __forceinline__ unsigned pack_hl(float v){
    const unsigned short hi = bhi(v);
    const unsigned short lo = brne(v - bf(hi));
    return (((unsigned)hi) << 16) | (unsigned)lo;
}

// ---------------- prep: pack weights into B-fragment order, hi/lo bf16 -----------
// ws layout (ushort): [0]=BhB(W1^T) [16384]=BlB [32768]=BhC(W1) [49152]=BlC
//                     [65536]=W0h stage-D (2048) [67584]=W0l (2048)
//                     [69632]=Ah stage-A (W0^T + bias k-slot, 4096) [73728]=Al (4096)
// v13 kernel reads only the *hi* B-operands (2-pass); lo sections kept for layout.
__global__ void prep_frags(const float* __restrict__ W1, const float* __restrict__ W0,
                           const float* __restrict__ b0, unsigned short* __restrict__ ws){
    const int t = blockIdx.x * 256 + threadIdx.x;
    if (t < 16384) {
        const int r = t & 7, l = (t >> 3) & 63, tile = t >> 9;
        const int nt = tile >> 2, ks = tile & 3;
        const int m = l >> 4, c = l & 15;
        const int k = ks * 32 + m * 8 + r;
        {
            const float v = W1[(nt * 16 + c) * HDIM + k];      // W1^T orientation (stage B)
            const unsigned short hi = bhi(v);
            ws[t]         = hi;
            ws[16384 + t] = brne(v - bf(hi));
        }
        {
            const float v = W1[k * HDIM + (nt * 16 + c)];      // W1 orientation (stage C)
            const unsigned short hi = bhi(v);
            ws[32768 + t] = hi;
            ws[49152 + t] = brne(v - bf(hi));
        }
    } else if (t < 18432) {
        const int t2 = t - 16384;                              // W0 B-frag (stage D)
        const int r = t2 & 7, l = (t2 >> 3) & 63, ks = t2 >> 9;
        const int m = l >> 4, c = l & 15;
        const int k = ks * 32 + m * 8 + r;
        const float v = (c < 8) ? W0[k * 8 + c] : 0.f;         // cols 8..15 zero
        const unsigned short hi = bhi(v);
        ws[65536 + t2] = hi;
        ws[67584 + t2] = brne(v - bf(hi));
    } else if (t < 22528) {
        const int t3 = t - 18432;                              // stage-A B-frag: W0^T + bias
        const int r = t3 & 7, l = (t3 >> 3) & 63, nt = t3 >> 9;   // nt 0..7, ks=0 only
        const int m = l >> 4, c = l & 15;
        const int k = m * 8 + r;                               // 0..31
        const int j = nt * 16 + c;
        float v = 0.f;
        if (k < 8)       v = W0[j * 8 + k];
        else if (k == 8) v = b0[j];                            // bias k-slot
        const unsigned short hi = bhi(v);
        ws[69632 + t3] = hi;
        ws[73728 + t3] = brne(v - bf(hi));
    }
}

// ---------------- v13: 2-pass split precision (drop weight-lo MFMA pass) ---------
// v12 counters: MFMA 18%/VALU 38%, ~44% stall; FR B-frag L1 return ~12us/CU, 1/3 of
// it weight-lo fragments buying precision we don't need (absmax 0.031 vs thr 0.2125).
// v13: every GEMM = (Ah+Al)xBh (2 MFMA passes, activations full hi/lo, weights bf16
// trunc, ~0.2% weight quantization). MFMA count -33%, FR traffic -50%.
// Barrier 0 also deleted: each wave duplicate-stages the xa rows its stage A reads
// (identical-value cross-wave LDS writes are benign). 4 barriers total.
__global__ __launch_bounds__(NT)
void dyn_mfma(const float* __restrict__ X, const float* __restrict__ Km,
              const float* __restrict__ Dm, const float* __restrict__ b1,
              const float* __restrict__ W2, const unsigned short* __restrict__ FR,
              float* __restrict__ out)
{
    __shared__ __align__(16) unsigned short act_hi[32 * ASTR];  // 8704 B
    __shared__ __align__(16) unsigned short act_lo[32 * ASTR];  // 8704 B
    __shared__ __align__(16) unsigned int   upk[16 * PSTR];     // 8448 B (a0 f32 -> u0 packed)
    __shared__ __align__(16) unsigned short xa_hi[256];         // 512 B (rows: 2s=x, 2s+1=v)
    __shared__ __align__(16) unsigned short xa_lo[256];         // 512 B
    __shared__ float xt[S * 16];                                // 1 KB (fp32, force)
    __shared__ float hvb[2][16];
    __shared__ float hvc[4][16];                                // -> 28.3 KB total

    const int tid = threadIdx.x;
    const long base = (long)blockIdx.x * S;

    const int wv = tid >> 6, l = tid & 63;
    const int m = l >> 4, c = l & 15;
    const int mt = wv >> 1, nh = wv & 1;   // m-tile (8 samples) x n-half

    // ---------------- pre-stage: X -> xt (all threads) + xa (per-wave dup) -------
    {
        xt[tid] = X[base * 16 + tid];
        // wave wv duplicate-stages the xa rows its OWN stage A reads (mt*128..+127):
        // waves {0,1} write rows 0..15, waves {2,3} rows 16..31 — identical values.
        const int i0 = mt * 128 + l;
        const float xv0 = X[base * 16 + i0];
        const float xv1 = X[base * 16 + i0 + 64];
        unsigned short h0w = bhi(xv0);
        xa_hi[i0] = h0w;           xa_lo[i0] = brne(xv0 - bf(h0w));
        h0w = bhi(xv1);
        xa_hi[i0 + 64] = h0w;      xa_lo[i0 + 64] = brne(xv1 - bf(h0w));
    }

    // preload stage-A B-frags (hi only, 2-pass)
    bf16x8 afh[4];
    #pragma unroll
    for (int n = 0; n < 4; ++n) {
        const int gi = (((nh * 4 + n) * 64) + l) * 8;
        afh[n] = *(const bf16x8*)&FR[69632 + gi];
    }
    // NO barrier: xa rows this wave reads were written by this wave.

    // ---------------- stage A: [z|dz] = xa x (W0^T + bias) via MFMA (2-pass) -----
    f32x4 accA[4];
    #pragma unroll
    for (int n = 0; n < 4; ++n) accA[n] = (f32x4){0.f, 0.f, 0.f, 0.f};
    {
        bf16x8 axh = {0,0,0,0,0,0,0,0}, axl = {0,0,0,0,0,0,0,0};
        if (m == 0) {                  // k=0..7: x (even rows) / v (odd rows)
            axh = *(const bf16x8*)&xa_hi[(mt * 16 + c) * 8];
            axl = *(const bf16x8*)&xa_lo[(mt * 16 + c) * 8];
        } else if (m == 1) {           // k=8 bias slot: 1.0 on x-rows only
            axh[0] = (short)(((c & 1) == 0) ? 0x3F80 : 0);
        }
        #pragma unroll
        for (int n = 0; n < 4; ++n) {
            accA[n] = __builtin_amdgcn_mfma_f32_16x16x32_bf16(axh, afh[n], accA[n], 0, 0, 0);
            accA[n] = __builtin_amdgcn_mfma_f32_16x16x32_bf16(axl, afh[n], accA[n], 0, 0, 0);
        }
    }

    // ---- stage A epilogue: h/dh -> act rows (bf16 hi/lo); a0 -> upk (raw f32) ---
    #pragma unroll
    for (int n = 0; n < 4; ++n) {
        const int j = (nh * 4 + n) * 16 + c;
        #pragma unroll
        for (int pr = 0; pr < 2; ++pr) {
            const int s = mt * 8 + 2 * m + pr;
            const float z  = accA[n][2 * pr];       // bias already included
            const float dz = accA[n][2 * pr + 1];
            const float h  = tanh_fast(z);
            const float e  = fmaf(-h, h, 1.f);
            const float dh = e * dz;
            const float a0 = -2.f * h * dh * dz;
            unsigned short t16 = bhi(h);
            act_hi[(2 * s) * ASTR + j] = t16;
            act_lo[(2 * s) * ASTR + j] = brne(h - bf(t16));
            t16 = bhi(dh);
            act_hi[(2 * s + 1) * ASTR + j] = t16;
            act_lo[(2 * s + 1) * ASTR + j] = brne(dh - bf(t16));
            upk[s * PSTR + j] = __float_as_uint(a0);
        }
    }

    // issue FIRST stage-B FR tile (hi only) + epilogue scalars before the barrier
    bf16x8 pbh[2][4];
    #pragma unroll
    for (int ks = 0; ks < 4; ++ks) {
        const int gi = (((nh * 4 + 0) * 4 + ks) * 64 + l) * 8;
        pbh[0][ks] = *(const bf16x8*)&FR[gi];
    }
    float b1v[4], w2v[4];
    #pragma unroll
    for (int n = 0; n < 4; ++n) {
        const int j = (nh * 4 + n) * 16 + c;
        b1v[n] = b1[j];
        w2v[n] = W2[j];
    }
    __syncthreads();   // barrier 1: act/a0 complete (cross-wave)

    // ---------------- stage B: [z1|dz1] = act x W1^T (2-pass MFMA) ---------------
    f32x4 accB[4];
    #pragma unroll
    for (int n = 0; n < 4; ++n) accB[n] = (f32x4){0.f, 0.f, 0.f, 0.f};
    {
        const int arow = mt * 16 + c;
        bf16x8 ah[4], al[4];
        #pragma unroll
        for (int ks = 0; ks < 4; ++ks) {
            ah[ks] = *(const bf16x8*)&act_hi[arow * ASTR + ks * 32 + m * 8];
            al[ks] = *(const bf16x8*)&act_lo[arow * ASTR + ks * 32 + m * 8];
        }
        #pragma unroll
        for (int n = 0; n < 4; ++n) {
            const int cur = n & 1;
            if (n < 3) {               // prefetch next n-tile (4 frags in flight)
                #pragma unroll
                for (int ks = 0; ks < 4; ++ks) {
                    const int gi = (((nh * 4 + n + 1) * 4 + ks) * 64 + l) * 8;
                    pbh[cur ^ 1][ks] = *(const bf16x8*)&FR[gi];
                }
            }
            #pragma unroll
            for (int ks = 0; ks < 4; ++ks) {
                accB[n] = __builtin_amdgcn_mfma_f32_16x16x32_bf16(ah[ks], pbh[cur][ks], accB[n], 0, 0, 0);
                accB[n] = __builtin_amdgcn_mfma_f32_16x16x32_bf16(al[ks], pbh[cur][ks], accB[n], 0, 0, 0);
            }
        }
    }

    // ---- stage B epilogue, part 1: u1/hvv into REGISTERS only -------------------
    const int sA = mt * 8 + 2 * m, sB = sA + 1;
    float u1Av[4], u1Bv[4];
    float hvA = 0.f, hvB = 0.f;
    #pragma unroll
    for (int n = 0; n < 4; ++n) {
        const float zA = accB[n][0] + b1v[n], dzA = accB[n][1];
        const float zB = accB[n][2] + b1v[n], dzB = accB[n][3];
        const float h1A = tanh_fast(zA), e1A = fmaf(-h1A, h1A, 1.f);
        u1Av[n] = w2v[n] * e1A;
        hvA = fmaf(-2.f * w2v[n] * h1A * e1A, dzA * dzA, hvA);
        const float h1B = tanh_fast(zB), e1B = fmaf(-h1B, h1B, 1.f);
        u1Bv[n] = w2v[n] * e1B;
        hvB = fmaf(-2.f * w2v[n] * h1B * e1B, dzB * dzB, hvB);
    }
    #pragma unroll
    for (int mk = 1; mk <= 8; mk <<= 1) {
        hvA += __shfl_xor(hvA, mk);
        hvB += __shfl_xor(hvB, mk);
    }

    // issue ALL stage-C FR frags (hi only) before the barriers
    bf16x8 cbh[2][4];
    #pragma unroll
    for (int n2 = 0; n2 < 2; ++n2)
        #pragma unroll
        for (int ks = 0; ks < 4; ++ks) {
            const int gi = (((wv * 2 + n2) * 4 + ks) * 64 + l) * 8;
            cbh[n2][ks] = *(const bf16x8*)&FR[32768 + gi];
        }

    __syncthreads();   // barrier 2 (race fix): all waves done READING dh rows

    // ---- stage B epilogue, part 2: store u1 over the dead dh rows ---------------
    #pragma unroll
    for (int n = 0; n < 4; ++n) {
        const int j = (nh * 4 + n) * 16 + c;
        unsigned short uh = bhi(u1Av[n]);
        act_hi[(2 * sA + 1) * ASTR + j] = uh;
        act_lo[(2 * sA + 1) * ASTR + j] = brne(u1Av[n] - bf(uh));
        uh = bhi(u1Bv[n]);
        act_hi[(2 * sB + 1) * ASTR + j] = uh;
        act_lo[(2 * sB + 1) * ASTR + j] = brne(u1Bv[n] - bf(uh));
    }
    if (c == 0) { hvb[nh][sA] = hvA; hvb[nh][sB] = hvB; }
    __syncthreads();   // barrier 3: u1 complete

    // ---------------- stage C: t = u1 x W1 (2-pass MFMA) -------------------------
    f32x4 accC[2];
    accC[0] = (f32x4){0.f, 0.f, 0.f, 0.f};
    accC[1] = (f32x4){0.f, 0.f, 0.f, 0.f};
    {
        const int urow = 2 * c + 1;                             // u1 row of sample c
        bf16x8 uh4[4], ul4[4];
        #pragma unroll
        for (int ks = 0; ks < 4; ++ks) {
            uh4[ks] = *(const bf16x8*)&act_hi[urow * ASTR + ks * 32 + m * 8];
            ul4[ks] = *(const bf16x8*)&act_lo[urow * ASTR + ks * 32 + m * 8];
        }
        #pragma unroll
        for (int n2 = 0; n2 < 2; ++n2)
            #pragma unroll
            for (int ks = 0; ks < 4; ++ks) {
                accC[n2] = __builtin_amdgcn_mfma_f32_16x16x32_bf16(uh4[ks], cbh[n2][ks], accC[n2], 0, 0, 0);
                accC[n2] = __builtin_amdgcn_mfma_f32_16x16x32_bf16(ul4[ks], cbh[n2][ks], accC[n2], 0, 0, 0);
            }
    }

    // ---- stage C epilogue: hvv1 += a0.t ; u0 = e0*t packed, overwrites upk ------
    {
        float hv1[4] = {0.f, 0.f, 0.f, 0.f};
        #pragma unroll
        for (int n2 = 0; n2 < 2; ++n2) {
            const int i = (wv * 2 + n2) * 16 + c;
            #pragma unroll
            for (int p = 0; p < 4; ++p) {
                const int s = 4 * m + p;                        // D row -> sample
                const float tv = accC[n2][p];
                const float h0 = bf(act_hi[(2 * s) * ASTR + i]) + bf(act_lo[(2 * s) * ASTR + i]);
                const float a0 = __uint_as_float(upk[s * PSTR + i]);   // raw fp32
                const float e0 = fmaf(-h0, h0, 1.f);
                const float u0 = e0 * tv;
                hv1[p] = fmaf(a0, tv, hv1[p]);
                upk[s * PSTR + i] = pack_hl(u0);                // same-lane RMW, no race
            }
        }
        #pragma unroll
        for (int mk = 1; mk <= 8; mk <<= 1) {
            #pragma unroll
            for (int p = 0; p < 4; ++p) hv1[p] += __shfl_xor(hv1[p], mk);
        }
        if (c == 0) {
            #pragma unroll
            for (int p = 0; p < 4; ++p) hvc[wv][4 * m + p] = hv1[p];
        }
    }

    // issue stage-D FR frags (hi only) + K/D rows before barrier 4 (wave 0 only)
    bf16x8 dbh[4];
    float4 ka, kb, da, db;
    if (wv == 0) {
        #pragma unroll
        for (int ks = 0; ks < 4; ++ks) {
            const int gi = (ks * 64 + l) * 8;
            dbh[ks] = *(const bf16x8*)&FR[65536 + gi];
        }
        const int dd = c & 7;
        ka = ((const float4*)Km)[dd * 2]; kb = ((const float4*)Km)[dd * 2 + 1];
        da = ((const float4*)Dm)[dd * 2]; db = ((const float4*)Dm)[dd * 2 + 1];
    }
    __syncthreads();   // barrier 4 (last): u0/hv complete

    if (wv != 0) return;   // waves 1-3 done; wave 0 finishes the block

    // ---------------- stage D (wave 0): g = u0 x W0 (2-pass MFMA) ----------------
    f32x4 accG = (f32x4){0.f, 0.f, 0.f, 0.f};
    #pragma unroll
    for (int ks = 0; ks < 4; ++ks) {
        unsigned u[8];
        *(uint4*)&u[0] = *(const uint4*)&upk[c * PSTR + ks * 32 + m * 8];
        *(uint4*)&u[4] = *(const uint4*)&upk[c * PSTR + ks * 32 + m * 8 + 4];
        bf16x8 ah, al;
        #pragma unroll
        for (int j = 0; j < 8; ++j) {
            ah[j] = (short)(u[j] >> 16);
            al[j] = (short)(u[j] & 0xFFFFu);
        }
        accG = __builtin_amdgcn_mfma_f32_16x16x32_bf16(ah, dbh[ks], accG, 0, 0, 0);
        accG = __builtin_amdgcn_mfma_f32_16x16x32_bf16(al, dbh[ks], accG, 0, 0, 0);
    }

    // ---------------- tail (wave 0): force, alpha, output ------------------------
    {
        #pragma unroll
        for (int p = 0; p < 4; ++p) {
            const int s = 4 * m + p;
            const float g = accG[p];                            // g[s][c] (c<8; else 0)
            const float hvv = hvb[0][s] + hvb[1][s]
                            + hvc[0][s] + hvc[1][s] + hvc[2][s] + hvc[3][s];
            const float* xv = &xt[s * 16];
            float f = ka.x * xv[0];
            f = fmaf(ka.y, xv[1], f);  f = fmaf(ka.z, xv[2], f);  f = fmaf(ka.w, xv[3], f);
            f = fmaf(kb.x, xv[4], f);  f = fmaf(kb.y, xv[5], f);  f = fmaf(kb.z, xv[6], f);
            f = fmaf(kb.w, xv[7], f);
            f = fmaf(da.x, xv[8], f);  f = fmaf(da.y, xv[9], f);  f = fmaf(da.z, xv[10], f);
            f = fmaf(da.w, xv[11], f); f = fmaf(db.x, xv[12], f); f = fmaf(db.y, xv[13], f);
            f = fmaf(db.z, xv[14], f); f = fmaf(db.w, xv[15], f);
            f = -f;
            float pgf = g * f, pgg = g * g;                     // c>=8 lanes contribute 0
            #pragma unroll
            for (int mk = 1; mk <= 8; mk <<= 1) {
                pgf += __shfl_xor(pgf, mk);
                pgg += __shfl_xor(pgg, mk);
            }
            const float al_ = (pgf + hvv) * __builtin_amdgcn_rcpf(1.f + pgg);
            if (c < 8)
                out[(base + s) * 8 + c] = fmaf(-g, al_, f);
        }
    }
}

// ---------------- correct (slow) fallback if workspace too small -----------------
__global__ void dyn_naive(const float* __restrict__ X, const float* __restrict__ Km,
                          const float* __restrict__ Dm, const float* __restrict__ W0,
                          const float* __restrict__ b0, const float* __restrict__ W1,
                          const float* __restrict__ b1, const float* __restrict__ W2,
                          float* __restrict__ out)
{
    const long sidx = (long)blockIdx.x * 64 + threadIdx.x;
    const float* xv = X + sidx * 16;
    float h0[HDIM], dh0[HDIM], a0[HDIM], u1[HDIM];
    for (int k = 0; k < HDIM; ++k) {
        float z = b0[k], dz = 0.f;
        for (int d = 0; d < 8; ++d) { z = fmaf(W0[k*8+d], xv[d], z); dz = fmaf(W0[k*8+d], xv[8+d], dz); }
        const float h = tanhf(z), e = 1.f - h*h;
        h0[k] = h; dh0[k] = e*dz; a0[k] = -2.f*h*e*dz*dz;
    }
    float hvv = 0.f;
    for (int j = 0; j < HDIM; ++j) {
        float z = b1[j], dz = 0.f, cc = 0.f;
        for (int k = 0; k < HDIM; ++k) {
            const float w = W1[j*HDIM+k];
            z = fmaf(w, h0[k], z); dz = fmaf(w, dh0[k], dz); cc = fmaf(w, a0[k], cc);
        }
        const float h = tanhf(z), e = 1.f - h*h;
        u1[j] = W2[j]*e;
        hvv += W2[j]*(e*cc - 2.f*h*e*dz*dz);
    }
    float g[8] = {0,0,0,0,0,0,0,0};
    for (int k = 0; k < HDIM; ++k) {
        float t = 0.f;
        for (int j = 0; j < HDIM; ++j) t = fmaf(u1[j], W1[j*HDIM+k], t);
        const float u0 = (1.f - h0[k]*h0[k]) * t;
        for (int d = 0; d < 8; ++d) g[d] = fmaf(W0[k*8+d], u0, g[d]);
    }
    float fd[8], gf = 0.f, gg = 0.f;
    for (int d = 0; d < 8; ++d) {
        float a = 0.f;
        for (int k = 0; k < 8; ++k) { a = fmaf(Km[d*8+k], xv[k], a); a = fmaf(Dm[d*8+k], xv[8+k], a); }
        fd[d] = -a; gf = fmaf(g[d], fd[d], gf); gg = fmaf(g[d], g[d], gg);
    }
    const float al = (gf + hvv) / (1.f + gg);
    for (int d = 0; d < 8; ++d) out[sidx*8 + d] = fd[d] - g[d]*al;
}

extern "C" void kernel_launch(void* const* d_in, const int* in_sizes, int n_in,
                              void* d_out, int out_size, void* d_ws, size_t ws_size,
                              hipStream_t stream) {
    const float* X  = (const float*)d_in[0];
    const float* Km = (const float*)d_in[1];
    const float* Dm = (const float*)d_in[2];
    const float* W0 = (const float*)d_in[3];
    const float* b0 = (const float*)d_in[4];
    const float* W1 = (const float*)d_in[5];
    const float* b1 = (const float*)d_in[6];
    const float* W2 = (const float*)d_in[7];
    // d_in[8] = b2 (unused: cancels in grad/hessian/force)
    float* out = (float*)d_out;

    const int BATCH = in_sizes[0] / 16;        // 65536
    if (ws_size >= (size_t)(77824 * sizeof(unsigned short))) {   // 152 KiB
        unsigned short* FR = (unsigned short*)d_ws;
        prep_frags<<<88, 256, 0, stream>>>(W1, W0, b0, FR);
        dyn_mfma<<<BATCH / S, NT, 0, stream>>>(X, Km, Dm, b1, W2, FR, out);
    } else {
        dyn_naive<<<BATCH / 64, 64, 0, stream>>>(X, Km, Dm, W0, b0, W1, b1, W2, out);
    }
}

// Round 13
// 98.960 us; speedup vs baseline: 1.3904x; 1.0114x over previous
//
#include <hip/hip_runtime.h>
#include <math.h>

#define HDIM 128
#define S 16            // samples per workgroup
#define NT 256
#define ASTR 136        // bf16 row stride (ushort)
#define PSTR 132        // u32 row stride

typedef __attribute__((ext_vector_type(8))) short  bf16x8;   // MFMA A/B frag
typedef __attribute__((ext_vector_type(8))) unsigned short u16x8;
typedef __attribute__((ext_vector_type(4))) float  f32x4;    // MFMA C/D frag

// tanh(x) = 1 - 2/(exp(2x)+1): NaN-free for any x, abs err ~1e-7.
__device__ __forceinline__ float tanh_fast(float x){
    const float e = __expf(2.0f * x);
    return 1.0f - 2.0f * __builtin_amdgcn_rcpf(e + 1.0f);
}
// bf16 helpers
__device__ __forceinline__ unsigned short bhi(float v){              // truncate
    return (unsigned short)(__float_as_uint(v) >> 16);
}
__device__ __forceinline__ unsigned short brne(float v){             // round-nearest-even
    unsigned u = __float_as_uint(v);
    return (unsigned short)((u + 0x7FFFu + ((u >> 16) & 1u)) >> 16);
}
__device__ __forceinline__ float bf(unsigned short u){
    return __uint_as_float(((unsigned)u) << 16);
}

// ---------------- prep: pack weights into B-fragment order, RNE bf16 -------------
// v14: all weight fragments are single RNE bf16 (unbiased, 2x less error than the
// old truncated hi); lo sections are never read since v13 -> not written.
// ws layout (ushort): [0]=B(W1^T) [32768]=C(W1) [65536]=D(W0) [69632]=A(W0^T+bias)
__global__ void prep_frags(const float* __restrict__ W1, const float* __restrict__ W0,
                           const float* __restrict__ b0, unsigned short* __restrict__ ws){
    const int t = blockIdx.x * 256 + threadIdx.x;
    if (t < 16384) {
        const int r = t & 7, l = (t >> 3) & 63, tile = t >> 9;
        const int nt = tile >> 2, ks = tile & 3;
        const int m = l >> 4, c = l & 15;
        const int k = ks * 32 + m * 8 + r;
        ws[t]         = brne(W1[(nt * 16 + c) * HDIM + k]);    // W1^T (stage B)
        ws[32768 + t] = brne(W1[k * HDIM + (nt * 16 + c)]);    // W1   (stage C)
    } else if (t < 18432) {
        const int t2 = t - 16384;                              // W0 B-frag (stage D)
        const int r = t2 & 7, l = (t2 >> 3) & 63, ks = t2 >> 9;
        const int m = l >> 4, c = l & 15;
        const int k = ks * 32 + m * 8 + r;
        ws[65536 + t2] = (c < 8) ? brne(W0[k * 8 + c]) : (unsigned short)0;
    } else if (t < 22528) {
        const int t3 = t - 18432;                              // stage-A B-frag: W0^T + bias
        const int r = t3 & 7, l = (t3 >> 3) & 63, nt = t3 >> 9;
        const int m = l >> 4, c = l & 15;
        const int k = m * 8 + r;                               // 0..31
        const int j = nt * 16 + c;
        float v = 0.f;
        if (k < 8)       v = W0[j * 8 + k];
        else if (k == 8) v = b0[j];                            // bias k-slot
        ws[69632 + t3] = brne(v);
    }
}

// ---------------- v14: stage-C single-pass; RNE weights; u0 raw f32 --------------
// v13 landed <40us (kernel fell out of the rocprof top-5 behind the harness's 40us
// 268MB fill). Error headroom 0.0625 vs 0.2125 -> spend some: u1 stored as ONE RNE
// bf16 (stage C 16->8 MFMA/wave, no u1-lo writes/reads); all weight frags RNE
// (halves+unbiases weight error, buying the headroom back). u0 stored raw f32;
// hi/lo split deferred to stage D (wave 0 only).
__global__ __launch_bounds__(NT)
void dyn_mfma(const float* __restrict__ X, const float* __restrict__ Km,
              const float* __restrict__ Dm, const float* __restrict__ b1,
              const float* __restrict__ W2, const unsigned short* __restrict__ FR,
              float* __restrict__ out)
{
    __shared__ __align__(16) unsigned short act_hi[32 * ASTR];  // 8704 B
    __shared__ __align__(16) unsigned short act_lo[32 * ASTR];  // 8704 B
    __shared__ __align__(16) unsigned int   upk[16 * PSTR];     // 8448 B (a0 f32 -> u0 f32)
    __shared__ __align__(16) unsigned short xa_hi[256];         // 512 B (rows: 2s=x, 2s+1=v)
    __shared__ __align__(16) unsigned short xa_lo[256];         // 512 B
    __shared__ float xt[S * 16];                                // 1 KB (fp32, force)
    __shared__ float hvb[2][16];
    __shared__ float hvc[4][16];                                // -> 28.3 KB total

    const int tid = threadIdx.x;
    const long base = (long)blockIdx.x * S;

    const int wv = tid >> 6, l = tid & 63;
    const int m = l >> 4, c = l & 15;
    const int mt = wv >> 1, nh = wv & 1;   // m-tile (8 samples) x n-half

    // ---------------- pre-stage: X -> xt (all threads) + xa (per-wave dup) -------
    {
        xt[tid] = X[base * 16 + tid];
        // wave wv duplicate-stages the xa rows its OWN stage A reads
        const int i0 = mt * 128 + l;
        const float xv0 = X[base * 16 + i0];
        const float xv1 = X[base * 16 + i0 + 64];
        unsigned short h0w = bhi(xv0);
        xa_hi[i0] = h0w;           xa_lo[i0] = brne(xv0 - bf(h0w));
        h0w = bhi(xv1);
        xa_hi[i0 + 64] = h0w;      xa_lo[i0 + 64] = brne(xv1 - bf(h0w));
    }

    // preload stage-A B-frags
    bf16x8 afh[4];
    #pragma unroll
    for (int n = 0; n < 4; ++n) {
        const int gi = (((nh * 4 + n) * 64) + l) * 8;
        afh[n] = *(const bf16x8*)&FR[69632 + gi];
    }
    // NO barrier: xa rows this wave reads were written by this wave.

    // ---------------- stage A: [z|dz] = xa x (W0^T + bias) via MFMA (2-pass) -----
    f32x4 accA[4];
    #pragma unroll
    for (int n = 0; n < 4; ++n) accA[n] = (f32x4){0.f, 0.f, 0.f, 0.f};
    {
        bf16x8 axh = {0,0,0,0,0,0,0,0}, axl = {0,0,0,0,0,0,0,0};
        if (m == 0) {                  // k=0..7: x (even rows) / v (odd rows)
            axh = *(const bf16x8*)&xa_hi[(mt * 16 + c) * 8];
            axl = *(const bf16x8*)&xa_lo[(mt * 16 + c) * 8];
        } else if (m == 1) {           // k=8 bias slot: 1.0 on x-rows only
            axh[0] = (short)(((c & 1) == 0) ? 0x3F80 : 0);
        }
        #pragma unroll
        for (int n = 0; n < 4; ++n) {
            accA[n] = __builtin_amdgcn_mfma_f32_16x16x32_bf16(axh, afh[n], accA[n], 0, 0, 0);
            accA[n] = __builtin_amdgcn_mfma_f32_16x16x32_bf16(axl, afh[n], accA[n], 0, 0, 0);
        }
    }

    // ---- stage A epilogue: h/dh -> act rows (bf16 hi/lo); a0 -> upk (raw f32) ---
    #pragma unroll
    for (int n = 0; n < 4; ++n) {
        const int j = (nh * 4 + n) * 16 + c;
        #pragma unroll
        for (int pr = 0; pr < 2; ++pr) {
            const int s = mt * 8 + 2 * m + pr;
            const float z  = accA[n][2 * pr];       // bias already included
            const float dz = accA[n][2 * pr + 1];
            const float h  = tanh_fast(z);
            const float e  = fmaf(-h, h, 1.f);
            const float dh = e * dz;
            const float a0 = -2.f * h * dh * dz;
            unsigned short t16 = bhi(h);
            act_hi[(2 * s) * ASTR + j] = t16;
            act_lo[(2 * s) * ASTR + j] = brne(h - bf(t16));
            t16 = bhi(dh);
            act_hi[(2 * s + 1) * ASTR + j] = t16;
            act_lo[(2 * s + 1) * ASTR + j] = brne(dh - bf(t16));
            upk[s * PSTR + j] = __float_as_uint(a0);
        }
    }

    // issue FIRST stage-B FR tile + epilogue scalars before the barrier
    bf16x8 pbh[2][4];
    #pragma unroll
    for (int ks = 0; ks < 4; ++ks) {
        const int gi = (((nh * 4 + 0) * 4 + ks) * 64 + l) * 8;
        pbh[0][ks] = *(const bf16x8*)&FR[gi];
    }
    float b1v[4], w2v[4];
    #pragma unroll
    for (int n = 0; n < 4; ++n) {
        const int j = (nh * 4 + n) * 16 + c;
        b1v[n] = b1[j];
        w2v[n] = W2[j];
    }
    __syncthreads();   // barrier 1: act/a0 complete (cross-wave)

    // ---------------- stage B: [z1|dz1] = act x W1^T (2-pass: act hi+lo) ---------
    f32x4 accB[4];
    #pragma unroll
    for (int n = 0; n < 4; ++n) accB[n] = (f32x4){0.f, 0.f, 0.f, 0.f};
    {
        const int arow = mt * 16 + c;
        bf16x8 ah[4], al[4];
        #pragma unroll
        for (int ks = 0; ks < 4; ++ks) {
            ah[ks] = *(const bf16x8*)&act_hi[arow * ASTR + ks * 32 + m * 8];
            al[ks] = *(const bf16x8*)&act_lo[arow * ASTR + ks * 32 + m * 8];
        }
        #pragma unroll
        for (int n = 0; n < 4; ++n) {
            const int cur = n & 1;
            if (n < 3) {               // prefetch next n-tile
                #pragma unroll
                for (int ks = 0; ks < 4; ++ks) {
                    const int gi = (((nh * 4 + n + 1) * 4 + ks) * 64 + l) * 8;
                    pbh[cur ^ 1][ks] = *(const bf16x8*)&FR[gi];
                }
            }
            #pragma unroll
            for (int ks = 0; ks < 4; ++ks) {
                accB[n] = __builtin_amdgcn_mfma_f32_16x16x32_bf16(ah[ks], pbh[cur][ks], accB[n], 0, 0, 0);
                accB[n] = __builtin_amdgcn_mfma_f32_16x16x32_bf16(al[ks], pbh[cur][ks], accB[n], 0, 0, 0);
            }
        }
    }

    // ---- stage B epilogue, part 1: u1/hvv into REGISTERS only -------------------
    const int sA = mt * 8 + 2 * m, sB = sA + 1;
    float u1Av[4], u1Bv[4];
    float hvA = 0.f, hvB = 0.f;
    #pragma unroll
    for (int n = 0; n < 4; ++n) {
        const float zA = accB[n][0] + b1v[n], dzA = accB[n][1];
        const float zB = accB[n][2] + b1v[n], dzB = accB[n][3];
        const float h1A = tanh_fast(zA), e1A = fmaf(-h1A, h1A, 1.f);
        u1Av[n] = w2v[n] * e1A;
        hvA = fmaf(-2.f * w2v[n] * h1A * e1A, dzA * dzA, hvA);
        const float h1B = tanh_fast(zB), e1B = fmaf(-h1B, h1B, 1.f);
        u1Bv[n] = w2v[n] * e1B;
        hvB = fmaf(-2.f * w2v[n] * h1B * e1B, dzB * dzB, hvB);
    }
    #pragma unroll
    for (int mk = 1; mk <= 8; mk <<= 1) {
        hvA += __shfl_xor(hvA, mk);
        hvB += __shfl_xor(hvB, mk);
    }

    // issue ALL stage-C FR frags before the barriers
    bf16x8 cbh[2][4];
    #pragma unroll
    for (int n2 = 0; n2 < 2; ++n2)
        #pragma unroll
        for (int ks = 0; ks < 4; ++ks) {
            const int gi = (((wv * 2 + n2) * 4 + ks) * 64 + l) * 8;
            cbh[n2][ks] = *(const bf16x8*)&FR[32768 + gi];
        }

    __syncthreads();   // barrier 2 (race fix): all waves done READING dh rows

    // ---- stage B epilogue, part 2: store u1 (single RNE bf16) over dh-hi rows ---
    #pragma unroll
    for (int n = 0; n < 4; ++n) {
        const int j = (nh * 4 + n) * 16 + c;
        act_hi[(2 * sA + 1) * ASTR + j] = brne(u1Av[n]);
        act_hi[(2 * sB + 1) * ASTR + j] = brne(u1Bv[n]);
    }
    if (c == 0) { hvb[nh][sA] = hvA; hvb[nh][sB] = hvB; }
    __syncthreads();   // barrier 3: u1 complete

    // ---------------- stage C: t = u1 x W1 (single-pass MFMA) --------------------
    f32x4 accC[2];
    accC[0] = (f32x4){0.f, 0.f, 0.f, 0.f};
    accC[1] = (f32x4){0.f, 0.f, 0.f, 0.f};
    {
        const int urow = 2 * c + 1;                             // u1 row of sample c
        bf16x8 uh4[4];
        #pragma unroll
        for (int ks = 0; ks < 4; ++ks)
            uh4[ks] = *(const bf16x8*)&act_hi[urow * ASTR + ks * 32 + m * 8];
        #pragma unroll
        for (int n2 = 0; n2 < 2; ++n2)
            #pragma unroll
            for (int ks = 0; ks < 4; ++ks)
                accC[n2] = __builtin_amdgcn_mfma_f32_16x16x32_bf16(uh4[ks], cbh[n2][ks], accC[n2], 0, 0, 0);
    }

    // ---- stage C epilogue: hvv1 += a0.t ; u0 = e0*t raw f32, overwrites upk -----
    {
        float hv1[4] = {0.f, 0.f, 0.f, 0.f};
        #pragma unroll
        for (int n2 = 0; n2 < 2; ++n2) {
            const int i = (wv * 2 + n2) * 16 + c;
            #pragma unroll
            for (int p = 0; p < 4; ++p) {
                const int s = 4 * m + p;                        // D row -> sample
                const float tv = accC[n2][p];
                const float h0 = bf(act_hi[(2 * s) * ASTR + i]) + bf(act_lo[(2 * s) * ASTR + i]);
                const float a0 = __uint_as_float(upk[s * PSTR + i]);   // raw fp32
                const float e0 = fmaf(-h0, h0, 1.f);
                const float u0 = e0 * tv;
                hv1[p] = fmaf(a0, tv, hv1[p]);
                upk[s * PSTR + i] = __float_as_uint(u0);        // same-lane RMW, no race
            }
        }
        #pragma unroll
        for (int mk = 1; mk <= 8; mk <<= 1) {
            #pragma unroll
            for (int p = 0; p < 4; ++p) hv1[p] += __shfl_xor(hv1[p], mk);
        }
        if (c == 0) {
            #pragma unroll
            for (int p = 0; p < 4; ++p) hvc[wv][4 * m + p] = hv1[p];
        }
    }

    // issue stage-D FR frags + K/D rows before barrier 4 (wave 0 only uses them)
    bf16x8 dbh[4];
    float4 ka, kb, da, db;
    if (wv == 0) {
        #pragma unroll
        for (int ks = 0; ks < 4; ++ks) {
            const int gi = (ks * 64 + l) * 8;
            dbh[ks] = *(const bf16x8*)&FR[65536 + gi];
        }
        const int dd = c & 7;
        ka = ((const float4*)Km)[dd * 2]; kb = ((const float4*)Km)[dd * 2 + 1];
        da = ((const float4*)Dm)[dd * 2]; db = ((const float4*)Dm)[dd * 2 + 1];
    }
    __syncthreads();   // barrier 4 (last): u0/hv complete

    if (wv != 0) return;   // waves 1-3 done; wave 0 finishes the block

    // ---------------- stage D (wave 0): g = u0 x W0 (2-pass: u0 hi+lo) -----------
    f32x4 accG = (f32x4){0.f, 0.f, 0.f, 0.f};
    #pragma unroll
    for (int ks = 0; ks < 4; ++ks) {
        unsigned u[8];
        *(uint4*)&u[0] = *(const uint4*)&upk[c * PSTR + ks * 32 + m * 8];
        *(uint4*)&u[4] = *(const uint4*)&upk[c * PSTR + ks * 32 + m * 8 + 4];
        bf16x8 ah, al;
        #pragma unroll
        for (int j = 0; j < 8; ++j) {
            const float v = __uint_as_float(u[j]);
            const unsigned short h = bhi(v);
            ah[j] = (short)h;
            al[j] = (short)brne(v - bf(h));
        }
        accG = __builtin_amdgcn_mfma_f32_16x16x32_bf16(ah, dbh[ks], accG, 0, 0, 0);
        accG = __builtin_amdgcn_mfma_f32_16x16x32_bf16(al, dbh[ks], accG, 0, 0, 0);
    }

    // ---------------- tail (wave 0): force, alpha, output ------------------------
    {
        #pragma unroll
        for (int p = 0; p < 4; ++p) {
            const int s = 4 * m + p;
            const float g = accG[p];                            // g[s][c] (c<8; else 0)
            const float hvv = hvb[0][s] + hvb[1][s]
                            + hvc[0][s] + hvc[1][s] + hvc[2][s] + hvc[3][s];
            const float* xv = &xt[s * 16];
            float f = ka.x * xv[0];
            f = fmaf(ka.y, xv[1], f);  f = fmaf(ka.z, xv[2], f);  f = fmaf(ka.w, xv[3], f);
            f = fmaf(kb.x, xv[4], f);  f = fmaf(kb.y, xv[5], f);  f = fmaf(kb.z, xv[6], f);
            f = fmaf(kb.w, xv[7], f);
            f = fmaf(da.x, xv[8], f);  f = fmaf(da.y, xv[9], f);  f = fmaf(da.z, xv[10], f);
            f = fmaf(da.w, xv[11], f); f = fmaf(db.x, xv[12], f); f = fmaf(db.y, xv[13], f);
            f = fmaf(db.z, xv[14], f); f = fmaf(db.w, xv[15], f);
            f = -f;
            float pgf = g * f, pgg = g * g;                     // c>=8 lanes contribute 0
            #pragma unroll
            for (int mk = 1; mk <= 8; mk <<= 1) {
                pgf += __shfl_xor(pgf, mk);
                pgg += __shfl_xor(pgg, mk);
            }
            const float al_ = (pgf + hvv) * __builtin_amdgcn_rcpf(1.f + pgg);
            if (c < 8)
                out[(base + s) * 8 + c] = fmaf(-g, al_, f);
        }
    }
}

// ---------------- correct (slow) fallback if workspace too small -----------------
__global__ void dyn_naive(const float* __restrict__ X, const float* __restrict__ Km,
                          const float* __restrict__ Dm, const float* __restrict__ W0,
                          const float* __restrict__ b0, const float* __restrict__ W1,
                          const float* __restrict__ b1, const float* __restrict__ W2,
                          float* __restrict__ out)
{
    const long sidx = (long)blockIdx.x * 64 + threadIdx.x;
    const float* xv = X + sidx * 16;
    float h0[HDIM], dh0[HDIM], a0[HDIM], u1[HDIM];
    for (int k = 0; k < HDIM; ++k) {
        float z = b0[k], dz = 0.f;
        for (int d = 0; d < 8; ++d) { z = fmaf(W0[k*8+d], xv[d], z); dz = fmaf(W0[k*8+d], xv[8+d], dz); }
        const float h = tanhf(z), e = 1.f - h*h;
        h0[k] = h; dh0[k] = e*dz; a0[k] = -2.f*h*e*dz*dz;
    }
    float hvv = 0.f;
    for (int j = 0; j < HDIM; ++j) {
        float z = b1[j], dz = 0.f, cc = 0.f;
        for (int k = 0; k < HDIM; ++k) {
            const float w = W1[j*HDIM+k];
            z = fmaf(w, h0[k], z); dz = fmaf(w, dh0[k], dz); cc = fmaf(w, a0[k], cc);
        }
        const float h = tanhf(z), e = 1.f - h*h;
        u1[j] = W2[j]*e;
        hvv += W2[j]*(e*cc - 2.f*h*e*dz*dz);
    }
    float g[8] = {0,0,0,0,0,0,0,0};
    for (int k = 0; k < HDIM; ++k) {
        float t = 0.f;
        for (int j = 0; j < HDIM; ++j) t = fmaf(u1[j], W1[j*HDIM+k], t);
        const float u0 = (1.f - h0[k]*h0[k]) * t;
        for (int d = 0; d < 8; ++d) g[d] = fmaf(W0[k*8+d], u0, g[d]);
    }
    float fd[8], gf = 0.f, gg = 0.f;
    for (int d = 0; d < 8; ++d) {
        float a = 0.f;
        for (int k = 0; k < 8; ++k) { a = fmaf(Km[d*8+k], xv[k], a); a = fmaf(Dm[d*8+k], xv[8+k], a); }
        fd[d] = -a; gf = fmaf(g[d], fd[d], gf); gg = fmaf(g[d], g[d], gg);
    }
    const float al = (gf + hvv) / (1.f + gg);
    for (int d = 0; d < 8; ++d) out[sidx*8 + d] = fd[d] - g[d]*al;
}

extern "C" void kernel_launch(void* const* d_in, const int* in_sizes, int n_in,
                              void* d_out, int out_size, void* d_ws, size_t ws_size,
                              hipStream_t stream) {
    const float* X  = (const float*)d_in[0];
    const float* Km = (const float*)d_in[1];
    const float* Dm = (const float*)d_in[2];
    const float* W0 = (const float*)d_in[3];
    const float* b0 = (const float*)d_in[4];
    const float* W1 = (const float*)d_in[5];
    const float* b1 = (const float*)d_in[6];
    const float* W2 = (const float*)d_in[7];
    // d_in[8] = b2 (unused: cancels in grad/hessian/force)
    float* out = (float*)d_out;

    const int BATCH = in_sizes[0] / 16;        // 65536
    if (ws_size >= (size_t)(77824 * sizeof(unsigned short))) {   // 152 KiB
        unsigned short* FR = (unsigned short*)d_ws;
        prep_frags<<<88, 256, 0, stream>>>(W1, W0, b0, FR);
        dyn_mfma<<<BATCH / S, NT, 0, stream>>>(X, Km, Dm, b1, W2, FR, out);
    } else {
        dyn_naive<<<BATCH / 64, 64, 0, stream>>>(X, Km, Dm, W0, b0, W1, b1, W2, out);
    }
}

// Round 14
// 94.016 us; speedup vs baseline: 1.4635x; 1.0526x over previous
//
#include <hip/hip_runtime.h>
#include <math.h>

#define HDIM 128
#define S 16            // samples per workgroup
#define NT 256
#define ASTR 136        // bf16 row stride (ushort)
#define PSTR 132        // u32 row stride

typedef __attribute__((ext_vector_type(8))) short  bf16x8;   // MFMA A/B frag
typedef __attribute__((ext_vector_type(8))) unsigned short u16x8;
typedef __attribute__((ext_vector_type(4))) float  f32x4;    // MFMA C/D frag

// tanh(x) = 1 - 2/(exp(2x)+1): NaN-free for any x, abs err ~1e-7.
__device__ __forceinline__ float tanh_fast(float x){
    const float e = __expf(2.0f * x);
    return 1.0f - 2.0f * __builtin_amdgcn_rcpf(e + 1.0f);
}
// bf16 helpers
__device__ __forceinline__ unsigned short bhi(float v){              // truncate
    return (unsigned short)(__float_as_uint(v) >> 16);
}
__device__ __forceinline__ unsigned short brne(float v){             // round-nearest-even
    unsigned u = __float_as_uint(v);
    return (unsigned short)((u + 0x7FFFu + ((u >> 16) & 1u)) >> 16);
}
__device__ __forceinline__ float bf(unsigned short u){
    return __uint_as_float(((unsigned)u) << 16);
}

// ---------------- prep: pack weights into B-fragment order, RNE bf16 -------------
// ws layout (ushort): [0]=B(W1^T) [32768]=C(W1) [65536]=D(W0) [69632]=A(W0^T+bias)
__global__ void prep_frags(const float* __restrict__ W1, const float* __restrict__ W0,
                           const float* __restrict__ b0, unsigned short* __restrict__ ws){
    const int t = blockIdx.x * 256 + threadIdx.x;
    if (t < 16384) {
        const int r = t & 7, l = (t >> 3) & 63, tile = t >> 9;
        const int nt = tile >> 2, ks = tile & 3;
        const int m = l >> 4, c = l & 15;
        const int k = ks * 32 + m * 8 + r;
        ws[t]         = brne(W1[(nt * 16 + c) * HDIM + k]);    // W1^T (stage B)
        ws[32768 + t] = brne(W1[k * HDIM + (nt * 16 + c)]);    // W1   (stage C)
    } else if (t < 18432) {
        const int t2 = t - 16384;                              // W0 B-frag (stage D)
        const int r = t2 & 7, l = (t2 >> 3) & 63, ks = t2 >> 9;
        const int m = l >> 4, c = l & 15;
        const int k = ks * 32 + m * 8 + r;
        ws[65536 + t2] = (c < 8) ? brne(W0[k * 8 + c]) : (unsigned short)0;
    } else if (t < 22528) {
        const int t3 = t - 18432;                              // stage-A B-frag: W0^T + bias
        const int r = t3 & 7, l = (t3 >> 3) & 63, nt = t3 >> 9;
        const int m = l >> 4, c = l & 15;
        const int k = m * 8 + r;                               // 0..31
        const int j = nt * 16 + c;
        float v = 0.f;
        if (k < 8)       v = W0[j * 8 + k];
        else if (k == 8) v = b0[j];                            // bias k-slot
        ws[69632 + t3] = brne(v);
    }
}

// ---------------- v15: single-bf16 activations -> 19.6 KB LDS, 8 blocks/CU -------
// v14 stalled at ~38us kernel with occupancy ~31% (LDS 28.3KB = 5 blocks/CU); v11
// measured the occupancy elasticity (5->3 blocks cost ~10%). v15 drops act_lo:
// h/dh stored as ONE RNE bf16 (act-rounding err ~0.0007 on z1 — below the existing
// u1-bf16 rounding; e0 tail-error bounded because a0 stays fp32 from stage A).
// Wins: LDS 28.3->19.6KB (8 blocks/CU), stage B 32->16 MFMA, simpler epilogues.
__global__ __launch_bounds__(NT)
void dyn_mfma(const float* __restrict__ X, const float* __restrict__ Km,
              const float* __restrict__ Dm, const float* __restrict__ b1,
              const float* __restrict__ W2, const unsigned short* __restrict__ FR,
              float* __restrict__ out)
{
    __shared__ __align__(16) unsigned short act[32 * ASTR];     // 8704 B (h/dh/u1, RNE bf16)
    __shared__ __align__(16) unsigned int   upk[16 * PSTR];     // 8448 B (a0 f32 -> u0 f32)
    __shared__ __align__(16) unsigned short xa_hi[256];         // 512 B (rows: 2s=x, 2s+1=v)
    __shared__ __align__(16) unsigned short xa_lo[256];         // 512 B
    __shared__ float xt[S * 16];                                // 1 KB (fp32, force)
    __shared__ float hvb[2][16];
    __shared__ float hvc[4][16];                                // -> ~19.6 KB total

    const int tid = threadIdx.x;
    const long base = (long)blockIdx.x * S;

    const int wv = tid >> 6, l = tid & 63;
    const int m = l >> 4, c = l & 15;
    const int mt = wv >> 1, nh = wv & 1;   // m-tile (8 samples) x n-half

    // ---------------- pre-stage: X -> xt (all threads) + xa (per-wave dup) -------
    {
        xt[tid] = X[base * 16 + tid];
        // wave wv duplicate-stages the xa rows its OWN stage A reads
        const int i0 = mt * 128 + l;
        const float xv0 = X[base * 16 + i0];
        const float xv1 = X[base * 16 + i0 + 64];
        unsigned short h0w = bhi(xv0);
        xa_hi[i0] = h0w;           xa_lo[i0] = brne(xv0 - bf(h0w));
        h0w = bhi(xv1);
        xa_hi[i0 + 64] = h0w;      xa_lo[i0 + 64] = brne(xv1 - bf(h0w));
    }

    // preload stage-A B-frags
    bf16x8 afh[4];
    #pragma unroll
    for (int n = 0; n < 4; ++n) {
        const int gi = (((nh * 4 + n) * 64) + l) * 8;
        afh[n] = *(const bf16x8*)&FR[69632 + gi];
    }
    // NO barrier: xa rows this wave reads were written by this wave.

    // ---------------- stage A: [z|dz] = xa x (W0^T + bias) via MFMA (2-pass) -----
    f32x4 accA[4];
    #pragma unroll
    for (int n = 0; n < 4; ++n) accA[n] = (f32x4){0.f, 0.f, 0.f, 0.f};
    {
        bf16x8 axh = {0,0,0,0,0,0,0,0}, axl = {0,0,0,0,0,0,0,0};
        if (m == 0) {                  // k=0..7: x (even rows) / v (odd rows)
            axh = *(const bf16x8*)&xa_hi[(mt * 16 + c) * 8];
            axl = *(const bf16x8*)&xa_lo[(mt * 16 + c) * 8];
        } else if (m == 1) {           // k=8 bias slot: 1.0 on x-rows only
            axh[0] = (short)(((c & 1) == 0) ? 0x3F80 : 0);
        }
        #pragma unroll
        for (int n = 0; n < 4; ++n) {
            accA[n] = __builtin_amdgcn_mfma_f32_16x16x32_bf16(axh, afh[n], accA[n], 0, 0, 0);
            accA[n] = __builtin_amdgcn_mfma_f32_16x16x32_bf16(axl, afh[n], accA[n], 0, 0, 0);
        }
    }

    // ---- stage A epilogue: h/dh -> act rows (RNE bf16); a0 -> upk (raw f32) -----
    #pragma unroll
    for (int n = 0; n < 4; ++n) {
        const int j = (nh * 4 + n) * 16 + c;
        #pragma unroll
        for (int pr = 0; pr < 2; ++pr) {
            const int s = mt * 8 + 2 * m + pr;
            const float z  = accA[n][2 * pr];       // bias already included
            const float dz = accA[n][2 * pr + 1];
            const float h  = tanh_fast(z);
            const float e  = fmaf(-h, h, 1.f);
            const float dh = e * dz;
            const float a0 = -2.f * h * dh * dz;
            act[(2 * s)     * ASTR + j] = brne(h);
            act[(2 * s + 1) * ASTR + j] = brne(dh);
            upk[s * PSTR + j] = __float_as_uint(a0);
        }
    }

    // issue FIRST stage-B FR tile + epilogue scalars before the barrier
    bf16x8 pbh[2][4];
    #pragma unroll
    for (int ks = 0; ks < 4; ++ks) {
        const int gi = (((nh * 4 + 0) * 4 + ks) * 64 + l) * 8;
        pbh[0][ks] = *(const bf16x8*)&FR[gi];
    }
    float b1v[4], w2v[4];
    #pragma unroll
    for (int n = 0; n < 4; ++n) {
        const int j = (nh * 4 + n) * 16 + c;
        b1v[n] = b1[j];
        w2v[n] = W2[j];
    }
    __syncthreads();   // barrier 1: act/a0 complete (cross-wave)

    // ---------------- stage B: [z1|dz1] = act x W1^T (single-pass MFMA) ----------
    f32x4 accB[4];
    #pragma unroll
    for (int n = 0; n < 4; ++n) accB[n] = (f32x4){0.f, 0.f, 0.f, 0.f};
    {
        const int arow = mt * 16 + c;
        bf16x8 ah[4];
        #pragma unroll
        for (int ks = 0; ks < 4; ++ks)
            ah[ks] = *(const bf16x8*)&act[arow * ASTR + ks * 32 + m * 8];
        #pragma unroll
        for (int n = 0; n < 4; ++n) {
            const int cur = n & 1;
            if (n < 3) {               // prefetch next n-tile
                #pragma unroll
                for (int ks = 0; ks < 4; ++ks) {
                    const int gi = (((nh * 4 + n + 1) * 4 + ks) * 64 + l) * 8;
                    pbh[cur ^ 1][ks] = *(const bf16x8*)&FR[gi];
                }
            }
            #pragma unroll
            for (int ks = 0; ks < 4; ++ks)
                accB[n] = __builtin_amdgcn_mfma_f32_16x16x32_bf16(ah[ks], pbh[cur][ks], accB[n], 0, 0, 0);
        }
    }

    // ---- stage B epilogue, part 1: u1/hvv into REGISTERS only -------------------
    const int sA = mt * 8 + 2 * m, sB = sA + 1;
    float u1Av[4], u1Bv[4];
    float hvA = 0.f, hvB = 0.f;
    #pragma unroll
    for (int n = 0; n < 4; ++n) {
        const float zA = accB[n][0] + b1v[n], dzA = accB[n][1];
        const float zB = accB[n][2] + b1v[n], dzB = accB[n][3];
        const float h1A = tanh_fast(zA), e1A = fmaf(-h1A, h1A, 1.f);
        u1Av[n] = w2v[n] * e1A;
        hvA = fmaf(-2.f * w2v[n] * h1A * e1A, dzA * dzA, hvA);
        const float h1B = tanh_fast(zB), e1B = fmaf(-h1B, h1B, 1.f);
        u1Bv[n] = w2v[n] * e1B;
        hvB = fmaf(-2.f * w2v[n] * h1B * e1B, dzB * dzB, hvB);
    }
    #pragma unroll
    for (int mk = 1; mk <= 8; mk <<= 1) {
        hvA += __shfl_xor(hvA, mk);
        hvB += __shfl_xor(hvB, mk);
    }

    // issue ALL stage-C FR frags before the barriers
    bf16x8 cbh[2][4];
    #pragma unroll
    for (int n2 = 0; n2 < 2; ++n2)
        #pragma unroll
        for (int ks = 0; ks < 4; ++ks) {
            const int gi = (((wv * 2 + n2) * 4 + ks) * 64 + l) * 8;
            cbh[n2][ks] = *(const bf16x8*)&FR[32768 + gi];
        }

    __syncthreads();   // barrier 2 (race fix): all waves done READING dh rows

    // ---- stage B epilogue, part 2: store u1 (RNE bf16) over the dead dh rows ----
    #pragma unroll
    for (int n = 0; n < 4; ++n) {
        const int j = (nh * 4 + n) * 16 + c;
        act[(2 * sA + 1) * ASTR + j] = brne(u1Av[n]);
        act[(2 * sB + 1) * ASTR + j] = brne(u1Bv[n]);
    }
    if (c == 0) { hvb[nh][sA] = hvA; hvb[nh][sB] = hvB; }
    __syncthreads();   // barrier 3: u1 complete

    // ---------------- stage C: t = u1 x W1 (single-pass MFMA) --------------------
    f32x4 accC[2];
    accC[0] = (f32x4){0.f, 0.f, 0.f, 0.f};
    accC[1] = (f32x4){0.f, 0.f, 0.f, 0.f};
    {
        const int urow = 2 * c + 1;                             // u1 row of sample c
        bf16x8 uh4[4];
        #pragma unroll
        for (int ks = 0; ks < 4; ++ks)
            uh4[ks] = *(const bf16x8*)&act[urow * ASTR + ks * 32 + m * 8];
        #pragma unroll
        for (int n2 = 0; n2 < 2; ++n2)
            #pragma unroll
            for (int ks = 0; ks < 4; ++ks)
                accC[n2] = __builtin_amdgcn_mfma_f32_16x16x32_bf16(uh4[ks], cbh[n2][ks], accC[n2], 0, 0, 0);
    }

    // ---- stage C epilogue: hvv1 += a0.t ; u0 = e0*t raw f32, overwrites upk -----
    {
        float hv1[4] = {0.f, 0.f, 0.f, 0.f};
        #pragma unroll
        for (int n2 = 0; n2 < 2; ++n2) {
            const int i = (wv * 2 + n2) * 16 + c;
            #pragma unroll
            for (int p = 0; p < 4; ++p) {
                const int s = 4 * m + p;                        // D row -> sample
                const float tv = accC[n2][p];
                const float h0 = bf(act[(2 * s) * ASTR + i]);   // single RNE bf16
                const float a0 = __uint_as_float(upk[s * PSTR + i]);   // raw fp32
                const float e0 = fmaf(-h0, h0, 1.f);
                const float u0 = e0 * tv;
                hv1[p] = fmaf(a0, tv, hv1[p]);
                upk[s * PSTR + i] = __float_as_uint(u0);        // same-lane RMW, no race
            }
        }
        #pragma unroll
        for (int mk = 1; mk <= 8; mk <<= 1) {
            #pragma unroll
            for (int p = 0; p < 4; ++p) hv1[p] += __shfl_xor(hv1[p], mk);
        }
        if (c == 0) {
            #pragma unroll
            for (int p = 0; p < 4; ++p) hvc[wv][4 * m + p] = hv1[p];
        }
    }

    // issue stage-D FR frags + K/D rows before barrier 4 (wave 0 only uses them)
    bf16x8 dbh[4];
    float4 ka, kb, da, db;
    if (wv == 0) {
        #pragma unroll
        for (int ks = 0; ks < 4; ++ks) {
            const int gi = (ks * 64 + l) * 8;
            dbh[ks] = *(const bf16x8*)&FR[65536 + gi];
        }
        const int dd = c & 7;
        ka = ((const float4*)Km)[dd * 2]; kb = ((const float4*)Km)[dd * 2 + 1];
        da = ((const float4*)Dm)[dd * 2]; db = ((const float4*)Dm)[dd * 2 + 1];
    }
    __syncthreads();   // barrier 4 (last): u0/hv complete

    if (wv != 0) return;   // waves 1-3 done; wave 0 finishes the block

    // ---------------- stage D (wave 0): g = u0 x W0 (2-pass: u0 hi+lo) -----------
    f32x4 accG = (f32x4){0.f, 0.f, 0.f, 0.f};
    #pragma unroll
    for (int ks = 0; ks < 4; ++ks) {
        unsigned u[8];
        *(uint4*)&u[0] = *(const uint4*)&upk[c * PSTR + ks * 32 + m * 8];
        *(uint4*)&u[4] = *(const uint4*)&upk[c * PSTR + ks * 32 + m * 8 + 4];
        bf16x8 ah, al;
        #pragma unroll
        for (int j = 0; j < 8; ++j) {
            const float v = __uint_as_float(u[j]);
            const unsigned short h = bhi(v);
            ah[j] = (short)h;
            al[j] = (short)brne(v - bf(h));
        }
        accG = __builtin_amdgcn_mfma_f32_16x16x32_bf16(ah, dbh[ks], accG, 0, 0, 0);
        accG = __builtin_amdgcn_mfma_f32_16x16x32_bf16(al, dbh[ks], accG, 0, 0, 0);
    }

    // ---------------- tail (wave 0): force, alpha, output ------------------------
    {
        #pragma unroll
        for (int p = 0; p < 4; ++p) {
            const int s = 4 * m + p;
            const float g = accG[p];                            // g[s][c] (c<8; else 0)
            const float hvv = hvb[0][s] + hvb[1][s]
                            + hvc[0][s] + hvc[1][s] + hvc[2][s] + hvc[3][s];
            const float* xv = &xt[s * 16];
            float f = ka.x * xv[0];
            f = fmaf(ka.y, xv[1], f);  f = fmaf(ka.z, xv[2], f);  f = fmaf(ka.w, xv[3], f);
            f = fmaf(kb.x, xv[4], f);  f = fmaf(kb.y, xv[5], f);  f = fmaf(kb.z, xv[6], f);
            f = fmaf(kb.w, xv[7], f);
            f = fmaf(da.x, xv[8], f);  f = fmaf(da.y, xv[9], f);  f = fmaf(da.z, xv[10], f);
            f = fmaf(da.w, xv[11], f); f = fmaf(db.x, xv[12], f); f = fmaf(db.y, xv[13], f);
            f = fmaf(db.z, xv[14], f); f = fmaf(db.w, xv[15], f);
            f = -f;
            float pgf = g * f, pgg = g * g;                     // c>=8 lanes contribute 0
            #pragma unroll
            for (int mk = 1; mk <= 8; mk <<= 1) {
                pgf += __shfl_xor(pgf, mk);
                pgg += __shfl_xor(pgg, mk);
            }
            const float al_ = (pgf + hvv) * __builtin_amdgcn_rcpf(1.f + pgg);
            if (c < 8)
                out[(base + s) * 8 + c] = fmaf(-g, al_, f);
        }
    }
}

// ---------------- correct (slow) fallback if workspace too small -----------------
__global__ void dyn_naive(const float* __restrict__ X, const float* __restrict__ Km,
                          const float* __restrict__ Dm, const float* __restrict__ W0,
                          const float* __restrict__ b0, const float* __restrict__ W1,
                          const float* __restrict__ b1, const float* __restrict__ W2,
                          float* __restrict__ out)
{
    const long sidx = (long)blockIdx.x * 64 + threadIdx.x;
    const float* xv = X + sidx * 16;
    float h0[HDIM], dh0[HDIM], a0[HDIM], u1[HDIM];
    for (int k = 0; k < HDIM; ++k) {
        float z = b0[k], dz = 0.f;
        for (int d = 0; d < 8; ++d) { z = fmaf(W0[k*8+d], xv[d], z); dz = fmaf(W0[k*8+d], xv[8+d], dz); }
        const float h = tanhf(z), e = 1.f - h*h;
        h0[k] = h; dh0[k] = e*dz; a0[k] = -2.f*h*e*dz*dz;
    }
    float hvv = 0.f;
    for (int j = 0; j < HDIM; ++j) {
        float z = b1[j], dz = 0.f, cc = 0.f;
        for (int k = 0; k < HDIM; ++k) {
            const float w = W1[j*HDIM+k];
            z = fmaf(w, h0[k], z); dz = fmaf(w, dh0[k], dz); cc = fmaf(w, a0[k], cc);
        }
        const float h = tanhf(z), e = 1.f - h*h;
        u1[j] = W2[j]*e;
        hvv += W2[j]*(e*cc - 2.f*h*e*dz*dz);
    }
    float g[8] = {0,0,0,0,0,0,0,0};
    for (int k = 0; k < HDIM; ++k) {
        float t = 0.f;
        for (int j = 0; j < HDIM; ++j) t = fmaf(u1[j], W1[j*HDIM+k], t);
        const float u0 = (1.f - h0[k]*h0[k]) * t;
        for (int d = 0; d < 8; ++d) g[d] = fmaf(W0[k*8+d], u0, g[d]);
    }
    float fd[8], gf = 0.f, gg = 0.f;
    for (int d = 0; d < 8; ++d) {
        float a = 0.f;
        for (int k = 0; k < 8; ++k) { a = fmaf(Km[d*8+k], xv[k], a); a = fmaf(Dm[d*8+k], xv[8+k], a); }
        fd[d] = -a; gf = fmaf(g[d], fd[d], gf); gg = fmaf(g[d], g[d], gg);
    }
    const float al = (gf + hvv) / (1.f + gg);
    for (int d = 0; d < 8; ++d) out[sidx*8 + d] = fd[d] - g[d]*al;
}

extern "C" void kernel_launch(void* const* d_in, const int* in_sizes, int n_in,
                              void* d_out, int out_size, void* d_ws, size_t ws_size,
                              hipStream_t stream) {
    const float* X  = (const float*)d_in[0];
    const float* Km = (const float*)d_in[1];
    const float* Dm = (const float*)d_in[2];
    const float* W0 = (const float*)d_in[3];
    const float* b0 = (const float*)d_in[4];
    const float* W1 = (const float*)d_in[5];
    const float* b1 = (const float*)d_in[6];
    const float* W2 = (const float*)d_in[7];
    // d_in[8] = b2 (unused: cancels in grad/hessian/force)
    float* out = (float*)d_out;

    const int BATCH = in_sizes[0] / 16;        // 65536
    if (ws_size >= (size_t)(77824 * sizeof(unsigned short))) {   // 152 KiB
        unsigned short* FR = (unsigned short*)d_ws;
        prep_frags<<<88, 256, 0, stream>>>(W1, W0, b0, FR);
        dyn_mfma<<<BATCH / S, NT, 0, stream>>>(X, Km, Dm, b1, W2, FR, out);
    } else {
        dyn_naive<<<BATCH / 64, 64, 0, stream>>>(X, Km, Dm, W0, b0, W1, b1, W2, out);
    }
}

// Round 15
// 93.368 us; speedup vs baseline: 1.4736x; 1.0069x over previous
//
#include <hip/hip_runtime.h>
#include <math.h>

#define HDIM 128
#define S 32            // samples per workgroup (two sequential 16-sample halves)
#define NT 256
#define ASTR 136        // bf16 row stride (ushort); row pitch 272B, b128-aligned

typedef __attribute__((ext_vector_type(8))) short  bf16x8;   // MFMA A/B frag
typedef __attribute__((ext_vector_type(4))) float  f32x4;    // MFMA C/D frag

// tanh(x) = 1 - 2/(exp(2x)+1): NaN-free for any x, abs err ~1e-7.
__device__ __forceinline__ float tanh_fast(float x){
    const float e = __expf(2.0f * x);
    return 1.0f - 2.0f * __builtin_amdgcn_rcpf(e + 1.0f);
}
// bf16 helpers
__device__ __forceinline__ unsigned short bhi(float v){              // truncate
    return (unsigned short)(__float_as_uint(v) >> 16);
}
__device__ __forceinline__ unsigned short brne(float v){             // round-nearest-even
    unsigned u = __float_as_uint(v);
    return (unsigned short)((u + 0x7FFFu + ((u >> 16) & 1u)) >> 16);
}
__device__ __forceinline__ float bf(unsigned short u){
    return __uint_as_float(((unsigned)u) << 16);
}

// ---------------- prep: pack weights into B-fragment order, RNE bf16 -------------
// ws layout (ushort): [0]=B(W1^T) [32768]=C(W1) [65536]=D(W0) [69632]=A(W0^T+bias)
__global__ void prep_frags(const float* __restrict__ W1, const float* __restrict__ W0,
                           const float* __restrict__ b0, unsigned short* __restrict__ ws){
    const int t = blockIdx.x * 256 + threadIdx.x;
    if (t < 16384) {
        const int r = t & 7, l = (t >> 3) & 63, tile = t >> 9;
        const int nt = tile >> 2, ks = tile & 3;
        const int m = l >> 4, c = l & 15;
        const int k = ks * 32 + m * 8 + r;
        ws[t]         = brne(W1[(nt * 16 + c) * HDIM + k]);    // W1^T (stage B)
        ws[32768 + t] = brne(W1[k * HDIM + (nt * 16 + c)]);    // W1   (stage C)
    } else if (t < 18432) {
        const int t2 = t - 16384;                              // W0 B-frag (stage D)
        const int r = t2 & 7, l = (t2 >> 3) & 63, ks = t2 >> 9;
        const int m = l >> 4, c = l & 15;
        const int k = ks * 32 + m * 8 + r;
        ws[65536 + t2] = (c < 8) ? brne(W0[k * 8 + c]) : (unsigned short)0;
    } else if (t < 22528) {
        const int t3 = t - 18432;                              // stage-A B-frag: W0^T + bias
        const int r = t3 & 7, l = (t3 >> 3) & 63, nt = t3 >> 9;
        const int m = l >> 4, c = l & 15;
        const int k = m * 8 + r;                               // 0..31
        const int j = nt * 16 + c;
        float v = 0.f;
        if (k < 8)       v = W0[j * 8 + k];
        else if (k == 8) v = b0[j];                            // bias k-slot
        ws[69632 + t3] = brne(v);
    }
}

// ---------------- v16: S=32 via sequential halves, fragment reuse ----------------
// v15 kernel ~33us: costs scale with BLOCK count (FR L2 re-read ~116KB/block,
// 4 barriers/16 samples). v16 runs the v15 pipeline twice per block inside ONE
// barrier set: per-sample barriers halve, FR traffic halves (2048 blocks), stage-C
// frags loaded once and reused, stage-B's 2nd-half FR reload is L1-hot.
// a0/u0 stored as single RNE bf16 -> upk is ushort (stage D single-pass, no unpack);
// LDS ~31KB -> 5 blocks/CU (20 waves, vs v15's 32: v11 measured this elasticity mild).
__global__ __launch_bounds__(NT)
void dyn_mfma(const float* __restrict__ X, const float* __restrict__ Km,
              const float* __restrict__ Dm, const float* __restrict__ b1,
              const float* __restrict__ W2, const unsigned short* __restrict__ FR,
              float* __restrict__ out)
{
    __shared__ __align__(16) unsigned short act[64 * ASTR];     // 17408 B (h/dh/u1)
    __shared__ __align__(16) unsigned short upk[32 * ASTR];     //  8704 B (a0 -> u0, RNE bf16)
    __shared__ __align__(16) unsigned short xa_hi[512];         //  1024 B
    __shared__ __align__(16) unsigned short xa_lo[512];         //  1024 B
    __shared__ float xt[S * 16];                                //  2048 B (fp32, force)
    __shared__ float hvb[2][S];
    __shared__ float hvc[4][S];                                 // -> ~31 KB total

    const int tid = threadIdx.x;
    const long base = (long)blockIdx.x * S;

    const int wv = tid >> 6, l = tid & 63;
    const int m = l >> 4, c = l & 15;
    const int mt = wv >> 1, nh = wv & 1;   // m-tile (8 samples/half) x n-half

    // ---------------- pre-stage: X -> xt + xa (per-wave dup, both halves) --------
    {
        xt[tid]       = X[base * 16 + tid];
        xt[256 + tid] = X[base * 16 + 256 + tid];
        #pragma unroll
        for (int half = 0; half < 2; ++half) {
            const int i0 = half * 256 + mt * 128 + l;
            const float xv0 = X[base * 16 + i0];
            const float xv1 = X[base * 16 + i0 + 64];
            unsigned short hw = bhi(xv0);
            xa_hi[i0] = hw;        xa_lo[i0] = brne(xv0 - bf(hw));
            hw = bhi(xv1);
            xa_hi[i0 + 64] = hw;   xa_lo[i0 + 64] = brne(xv1 - bf(hw));
        }
    }

    // preload stage-A B-frags (shared by both halves)
    bf16x8 afh[4];
    #pragma unroll
    for (int n = 0; n < 4; ++n) {
        const int gi = (((nh * 4 + n) * 64) + l) * 8;
        afh[n] = *(const bf16x8*)&FR[69632 + gi];
    }
    // NO barrier: xa rows this wave reads were written by this wave.

    // ---------------- stage A (x2): [z|dz] = xa x (W0^T + bias), MFMA 2-pass -----
    #pragma unroll
    for (int half = 0; half < 2; ++half) {
        f32x4 accA[4];
        #pragma unroll
        for (int n = 0; n < 4; ++n) accA[n] = (f32x4){0.f, 0.f, 0.f, 0.f};
        {
            bf16x8 axh = {0,0,0,0,0,0,0,0}, axl = {0,0,0,0,0,0,0,0};
            if (m == 0) {              // k=0..7: x (even rows) / v (odd rows)
                axh = *(const bf16x8*)&xa_hi[half * 256 + (mt * 16 + c) * 8];
                axl = *(const bf16x8*)&xa_lo[half * 256 + (mt * 16 + c) * 8];
            } else if (m == 1) {       // k=8 bias slot: 1.0 on x-rows only
                axh[0] = (short)(((c & 1) == 0) ? 0x3F80 : 0);
            }
            #pragma unroll
            for (int n = 0; n < 4; ++n) {
                accA[n] = __builtin_amdgcn_mfma_f32_16x16x32_bf16(axh, afh[n], accA[n], 0, 0, 0);
                accA[n] = __builtin_amdgcn_mfma_f32_16x16x32_bf16(axl, afh[n], accA[n], 0, 0, 0);
            }
        }
        // epilogue: h/dh -> act rows (RNE bf16); a0 -> upk (RNE bf16)
        #pragma unroll
        for (int n = 0; n < 4; ++n) {
            const int j = (nh * 4 + n) * 16 + c;
            #pragma unroll
            for (int pr = 0; pr < 2; ++pr) {
                const int s = half * 16 + mt * 8 + 2 * m + pr;
                const float z  = accA[n][2 * pr];       // bias already included
                const float dz = accA[n][2 * pr + 1];
                const float h  = tanh_fast(z);
                const float e  = fmaf(-h, h, 1.f);
                const float dh = e * dz;
                const float a0 = -2.f * h * dh * dz;
                act[(2 * s)     * ASTR + j] = brne(h);
                act[(2 * s + 1) * ASTR + j] = brne(dh);
                upk[s * ASTR + j] = brne(a0);
            }
        }
    }

    // epilogue scalars (shared by both halves)
    float b1v[4], w2v[4];
    #pragma unroll
    for (int n = 0; n < 4; ++n) {
        const int j = (nh * 4 + n) * 16 + c;
        b1v[n] = b1[j];
        w2v[n] = W2[j];
    }
    __syncthreads();   // barrier 1: act/a0 complete (cross-wave), both halves

    // ---------------- stage B (x2): [z1|dz1] = act x W1^T, single-pass -----------
    float u1r[2][2][4];                // [half][sampleA/B][n]
    #pragma unroll
    for (int half = 0; half < 2; ++half) {
        const int arow = half * 32 + mt * 16 + c;
        bf16x8 ah[4];
        #pragma unroll
        for (int ks = 0; ks < 4; ++ks)
            ah[ks] = *(const bf16x8*)&act[arow * ASTR + ks * 32 + m * 8];
        bf16x8 pbh[2][4];
        #pragma unroll
        for (int ks = 0; ks < 4; ++ks) {
            const int gi = (((nh * 4 + 0) * 4 + ks) * 64 + l) * 8;
            pbh[0][ks] = *(const bf16x8*)&FR[gi];      // half1: L1-hot reload
        }
        f32x4 accB[4];
        #pragma unroll
        for (int n = 0; n < 4; ++n) accB[n] = (f32x4){0.f, 0.f, 0.f, 0.f};
        #pragma unroll
        for (int n = 0; n < 4; ++n) {
            const int cur = n & 1;
            if (n < 3) {
                #pragma unroll
                for (int ks = 0; ks < 4; ++ks) {
                    const int gi = (((nh * 4 + n + 1) * 4 + ks) * 64 + l) * 8;
                    pbh[cur ^ 1][ks] = *(const bf16x8*)&FR[gi];
                }
            }
            #pragma unroll
            for (int ks = 0; ks < 4; ++ks)
                accB[n] = __builtin_amdgcn_mfma_f32_16x16x32_bf16(ah[ks], pbh[cur][ks], accB[n], 0, 0, 0);
        }
        // epilogue: u1 -> registers; hvv part2 -> hvb
        const int sA = half * 16 + mt * 8 + 2 * m, sB = sA + 1;
        float hvA = 0.f, hvB = 0.f;
        #pragma unroll
        for (int n = 0; n < 4; ++n) {
            const float zA = accB[n][0] + b1v[n], dzA = accB[n][1];
            const float zB = accB[n][2] + b1v[n], dzB = accB[n][3];
            const float h1A = tanh_fast(zA), e1A = fmaf(-h1A, h1A, 1.f);
            u1r[half][0][n] = w2v[n] * e1A;
            hvA = fmaf(-2.f * w2v[n] * h1A * e1A, dzA * dzA, hvA);
            const float h1B = tanh_fast(zB), e1B = fmaf(-h1B, h1B, 1.f);
            u1r[half][1][n] = w2v[n] * e1B;
            hvB = fmaf(-2.f * w2v[n] * h1B * e1B, dzB * dzB, hvB);
        }
        #pragma unroll
        for (int mk = 1; mk <= 8; mk <<= 1) {
            hvA += __shfl_xor(hvA, mk);
            hvB += __shfl_xor(hvB, mk);
        }
        if (c == 0) { hvb[nh][sA] = hvA; hvb[nh][sB] = hvB; }
    }

    // preload ALL stage-C FR frags (shared across both halves)
    bf16x8 cbh[2][4];
    #pragma unroll
    for (int n2 = 0; n2 < 2; ++n2)
        #pragma unroll
        for (int ks = 0; ks < 4; ++ks) {
            const int gi = (((wv * 2 + n2) * 4 + ks) * 64 + l) * 8;
            cbh[n2][ks] = *(const bf16x8*)&FR[32768 + gi];
        }

    __syncthreads();   // barrier 2 (race fix): all waves done READING dh rows

    // ---- store u1 (RNE bf16) over the dead dh rows, both halves -----------------
    #pragma unroll
    for (int half = 0; half < 2; ++half) {
        const int sA = half * 16 + mt * 8 + 2 * m, sB = sA + 1;
        #pragma unroll
        for (int n = 0; n < 4; ++n) {
            const int j = (nh * 4 + n) * 16 + c;
            act[(2 * sA + 1) * ASTR + j] = brne(u1r[half][0][n]);
            act[(2 * sB + 1) * ASTR + j] = brne(u1r[half][1][n]);
        }
    }
    __syncthreads();   // barrier 3: u1 complete

    // ---------------- stage C (x2): t = u1 x W1, single-pass, cbh reused ---------
    #pragma unroll
    for (int half = 0; half < 2; ++half) {
        f32x4 accC[2];
        accC[0] = (f32x4){0.f, 0.f, 0.f, 0.f};
        accC[1] = (f32x4){0.f, 0.f, 0.f, 0.f};
        {
            const int urow = 2 * (half * 16 + c) + 1;          // u1 row of sample
            bf16x8 uh4[4];
            #pragma unroll
            for (int ks = 0; ks < 4; ++ks)
                uh4[ks] = *(const bf16x8*)&act[urow * ASTR + ks * 32 + m * 8];
            #pragma unroll
            for (int n2 = 0; n2 < 2; ++n2)
                #pragma unroll
                for (int ks = 0; ks < 4; ++ks)
                    accC[n2] = __builtin_amdgcn_mfma_f32_16x16x32_bf16(uh4[ks], cbh[n2][ks], accC[n2], 0, 0, 0);
        }
        // epilogue: hvv1 += a0.t ; u0 = e0*t (RNE bf16), overwrites upk
        float hv1[4] = {0.f, 0.f, 0.f, 0.f};
        #pragma unroll
        for (int n2 = 0; n2 < 2; ++n2) {
            const int i = (wv * 2 + n2) * 16 + c;
            #pragma unroll
            for (int p = 0; p < 4; ++p) {
                const int s = half * 16 + 4 * m + p;            // D row -> sample
                const float tv = accC[n2][p];
                const float h0 = bf(act[(2 * s) * ASTR + i]);
                const float a0 = bf(upk[s * ASTR + i]);
                const float e0 = fmaf(-h0, h0, 1.f);
                const float u0 = e0 * tv;
                hv1[p] = fmaf(a0, tv, hv1[p]);
                upk[s * ASTR + i] = brne(u0);                   // same-lane RMW, no race
            }
        }
        #pragma unroll
        for (int mk = 1; mk <= 8; mk <<= 1) {
            #pragma unroll
            for (int p = 0; p < 4; ++p) hv1[p] += __shfl_xor(hv1[p], mk);
        }
        if (c == 0) {
            #pragma unroll
            for (int p = 0; p < 4; ++p) hvc[wv][half * 16 + 4 * m + p] = hv1[p];
        }
    }

    // issue stage-D FR frags + K/D rows before barrier 4 (waves 0,1 use them)
    bf16x8 dbh[4];
    float4 ka, kb, da, db;
    if (wv < 2) {
        #pragma unroll
        for (int ks = 0; ks < 4; ++ks) {
            const int gi = (ks * 64 + l) * 8;
            dbh[ks] = *(const bf16x8*)&FR[65536 + gi];
        }
        const int dd = c & 7;
        ka = ((const float4*)Km)[dd * 2]; kb = ((const float4*)Km)[dd * 2 + 1];
        da = ((const float4*)Dm)[dd * 2]; db = ((const float4*)Dm)[dd * 2 + 1];
    }
    __syncthreads();   // barrier 4 (last): u0/hv complete

    if (wv >= 2) return;   // waves 2,3 done; waves 0,1 finish 16 samples each

    // ---------------- stage D: g = u0 x W0 (single-pass, u0 already bf16) --------
    f32x4 accG = (f32x4){0.f, 0.f, 0.f, 0.f};
    #pragma unroll
    for (int ks = 0; ks < 4; ++ks) {
        const bf16x8 ua = *(const bf16x8*)&upk[(wv * 16 + c) * ASTR + ks * 32 + m * 8];
        accG = __builtin_amdgcn_mfma_f32_16x16x32_bf16(ua, dbh[ks], accG, 0, 0, 0);
    }

    // ---------------- tail: force, alpha, output ---------------------------------
    {
        #pragma unroll
        for (int p = 0; p < 4; ++p) {
            const int s = wv * 16 + 4 * m + p;
            const float g = accG[p];                            // g[s][c] (c<8; else 0)
            const float hvv = hvb[0][s] + hvb[1][s]
                            + hvc[0][s] + hvc[1][s] + hvc[2][s] + hvc[3][s];
            const float* xv = &xt[s * 16];
            float f = ka.x * xv[0];
            f = fmaf(ka.y, xv[1], f);  f = fmaf(ka.z, xv[2], f);  f = fmaf(ka.w, xv[3], f);
            f = fmaf(kb.x, xv[4], f);  f = fmaf(kb.y, xv[5], f);  f = fmaf(kb.z, xv[6], f);
            f = fmaf(kb.w, xv[7], f);
            f = fmaf(da.x, xv[8], f);  f = fmaf(da.y, xv[9], f);  f = fmaf(da.z, xv[10], f);
            f = fmaf(da.w, xv[11], f); f = fmaf(db.x, xv[12], f); f = fmaf(db.y, xv[13], f);
            f = fmaf(db.z, xv[14], f); f = fmaf(db.w, xv[15], f);
            f = -f;
            float pgf = g * f, pgg = g * g;                     // c>=8 lanes contribute 0
            #pragma unroll
            for (int mk = 1; mk <= 8; mk <<= 1) {
                pgf += __shfl_xor(pgf, mk);
                pgg += __shfl_xor(pgg, mk);
            }
            const float al_ = (pgf + hvv) * __builtin_amdgcn_rcpf(1.f + pgg);
            if (c < 8)
                out[(base + s) * 8 + c] = fmaf(-g, al_, f);
        }
    }
}

// ---------------- correct (slow) fallback if workspace too small -----------------
__global__ void dyn_naive(const float* __restrict__ X, const float* __restrict__ Km,
                          const float* __restrict__ Dm, const float* __restrict__ W0,
                          const float* __restrict__ b0, const float* __restrict__ W1,
                          const float* __restrict__ b1, const float* __restrict__ W2,
                          float* __restrict__ out)
{
    const long sidx = (long)blockIdx.x * 64 + threadIdx.x;
    const float* xv = X + sidx * 16;
    float h0[HDIM], dh0[HDIM], a0[HDIM], u1[HDIM];
    for (int k = 0; k < HDIM; ++k) {
        float z = b0[k], dz = 0.f;
        for (int d = 0; d < 8; ++d) { z = fmaf(W0[k*8+d], xv[d], z); dz = fmaf(W0[k*8+d], xv[8+d], dz); }
        const float h = tanhf(z), e = 1.f - h*h;
        h0[k] = h; dh0[k] = e*dz; a0[k] = -2.f*h*e*dz*dz;
    }
    float hvv = 0.f;
    for (int j = 0; j < HDIM; ++j) {
        float z = b1[j], dz = 0.f, cc = 0.f;
        for (int k = 0; k < HDIM; ++k) {
            const float w = W1[j*HDIM+k];
            z = fmaf(w, h0[k], z); dz = fmaf(w, dh0[k], dz); cc = fmaf(w, a0[k], cc);
        }
        const float h = tanhf(z), e = 1.f - h*h;
        u1[j] = W2[j]*e;
        hvv += W2[j]*(e*cc - 2.f*h*e*dz*dz);
    }
    float g[8] = {0,0,0,0,0,0,0,0};
    for (int k = 0; k < HDIM; ++k) {
        float t = 0.f;
        for (int j = 0; j < HDIM; ++j) t = fmaf(u1[j], W1[j*HDIM+k], t);
        const float u0 = (1.f - h0[k]*h0[k]) * t;
        for (int d = 0; d < 8; ++d) g[d] = fmaf(W0[k*8+d], u0, g[d]);
    }
    float fd[8], gf = 0.f, gg = 0.f;
    for (int d = 0; d < 8; ++d) {
        float a = 0.f;
        for (int k = 0; k < 8; ++k) { a = fmaf(Km[d*8+k], xv[k], a); a = fmaf(Dm[d*8+k], xv[8+k], a); }
        fd[d] = -a; gf = fmaf(g[d], fd[d], gf); gg = fmaf(g[d], g[d], gg);
    }
    const float al = (gf + hvv) / (1.f + gg);
    for (int d = 0; d < 8; ++d) out[sidx*8 + d] = fd[d] - g[d]*al;
}

extern "C" void kernel_launch(void* const* d_in, const int* in_sizes, int n_in,
                              void* d_out, int out_size, void* d_ws, size_t ws_size,
                              hipStream_t stream) {
    const float* X  = (const float*)d_in[0];
    const float* Km = (const float*)d_in[1];
    const float* Dm = (const float*)d_in[2];
    const float* W0 = (const float*)d_in[3];
    const float* b0 = (const float*)d_in[4];
    const float* W1 = (const float*)d_in[5];
    const float* b1 = (const float*)d_in[6];
    const float* W2 = (const float*)d_in[7];
    // d_in[8] = b2 (unused: cancels in grad/hessian/force)
    float* out = (float*)d_out;

    const int BATCH = in_sizes[0] / 16;        // 65536
    if (ws_size >= (size_t)(77824 * sizeof(unsigned short))) {   // 152 KiB
        unsigned short* FR = (unsigned short*)d_ws;
        prep_frags<<<88, 256, 0, stream>>>(W1, W0, b0, FR);
        dyn_mfma<<<BATCH / S, NT, 0, stream>>>(X, Km, Dm, b1, W2, FR, out);
    } else {
        dyn_naive<<<BATCH / 64, 64, 0, stream>>>(X, Km, Dm, W0, b0, W1, b1, W2, out);
    }
}